// Round 1
// baseline (2866.612 us; speedup 1.0000x reference)
//
#include <hip/hip_runtime.h>
#include <hip/hip_cooperative_groups.h>
#include <float.h>

namespace cg = cooperative_groups;

#define NLVL 12
#define NB   16
#define NBLK 256    // blocks for deg_hist / fill node parts (per-block count arrays sized to this)
#define EBLK 2048   // blocks for edge-scatter kernels (grid-stride, no per-block state)

// meta: [96..109) base_f | [128..141) base_b | [160..177) base_o
// packed entry: id(18b) | fl(4b)<<18 | bl(4b)<<22 | tidx(4b)<<26   (N=200k < 2^18)
// tidx = nt*3+ninv in 0..8 -> h_init row = tabg[tidx]  (h_init never materialized)

struct Params {
    const int *nt, *ninv, *src, *dst, *fl, *bl, *batch;
    const float *We, *be, *Wf, *bf, *Wb, *bb;
    float *hN, *hB, *tabg, *out;
    int *rowptr, *cursor, *col, *nb_f, *nb_b, *onodes, *bsums, *meta, *plarr;
    int *cntf, *cntb, *cnto, *blkf, *blkb, *blko;
    int N, E, M, outN;
};

__device__ __forceinline__ float rlanef(float x, int l) {
    return __int_as_float(__builtin_amdgcn_readlane(__float_as_int(x), l));
}

// ---------------- edge-degree atomics (high-occupancy grid-stride) ----------
__global__ void k_edge_deg(Params p) {
    int g = blockIdx.x * 256 + threadIdx.x, gs = gridDim.x * 256;
    for (int e = g; e < p.E; e += gs) {
        atomicAdd(&p.rowptr[p.dst[e]], 1);
        atomicAdd(&p.rowptr[p.N + p.src[e]], 1);
    }
}

// ---------------- node histograms + packed (fl,bl,tidx) ----------------------
__global__ void k_deg_hist(Params p) {
    __shared__ int hf[NLVL], hb[NLVL], ho[NB];
    int tid = threadIdx.x, bid = blockIdx.x;
    if (tid < NLVL) { hf[tid] = 0; hb[tid] = 0; }
    if (tid < NB) ho[tid] = 0;
    __syncthreads();
    // chunk-owned nodes (same chunk map as k_fill!)
    int chunk = (p.N + gridDim.x - 1) / gridDim.x;
    int lo = bid * chunk, hi = lo + chunk; if (hi > p.N) hi = p.N;
    for (int i = lo + tid; i < hi; i += 256) {
        int f = p.fl[i], b = p.bl[i];
        int t = p.nt[i], iv = p.ninv[i];
        p.plarr[i] = f | (b << 4) | ((t * 3 + iv) << 8);
        atomicAdd(&hf[f], 1);
        atomicAdd(&hb[b], 1);
        if (t == 1) atomicAdd(&ho[p.batch[i]], 1);
    }
    __syncthreads();
    if (tid < NLVL) { p.cntf[tid * NBLK + bid] = hf[tid]; p.cntb[tid * NBLK + bid] = hb[tid]; }
    if (tid < NB) p.cnto[tid * NBLK + bid] = ho[tid];
}

// ---------------- 3-kernel exclusive scan over M = 2N ----------------
__global__ void k_scan1(int* __restrict__ data, int M, int* __restrict__ bsums) {
    __shared__ int s[512];
    int t = threadIdx.x;
    int g = blockIdx.x * 512 + t;
    int v = (g < M) ? data[g] : 0;
    s[t] = v;
    __syncthreads();
    for (int off = 1; off < 512; off <<= 1) {
        int add = (t >= off) ? s[t - off] : 0;
        __syncthreads();
        s[t] += add;
        __syncthreads();
    }
    if (g < M) data[g] = s[t] - v;
    if (t == 511) bsums[blockIdx.x] = s[511];
}

// scan_top: bsums scan + per-block-base segmented scans + meta bases + tabg + out init
__global__ void k_scan_top(int* __restrict__ bsums, int nblk, Params p,
                           float* __restrict__ out, int outN) {
    __shared__ int s[1024];
    __shared__ int tot[48];     // fwd [0..12), bwd [16..28), out [32..48)
    int t = threadIdx.x;
    int* meta = p.meta;
    for (int i = t; i < outN; i += 1024)
        out[i] = ((i & 127) < 64) ? -FLT_MAX : 0.0f;   // max-pool init == finfo.min
    if (t < 576) {              // 9-row h_init table
        int row = t >> 6, j = t & 63;
        float nf = (float)(row / 3), iv = (float)(row % 3);
        p.tabg[t] = fmaf(nf, p.We[j], fmaf(iv, p.We[64 + j], p.be[j]));
    }
    // segmented scans: 4 segments of NBLK=256 per round
    int seg = t >> 8, b = t & 255;
    for (int r = 0; r < 3; r++) {                      // fwd levels 4r+seg
        int l = 4 * r + seg;
        int v = p.cntf[l * NBLK + b];
        s[t] = v; __syncthreads();
        for (int off = 1; off < NBLK; off <<= 1) {
            int add = (b >= off) ? s[t - off] : 0; __syncthreads();
            s[t] += add; __syncthreads();
        }
        p.blkf[l * NBLK + b] = s[t] - v;
        if (b == NBLK - 1) tot[l] = s[t];
        __syncthreads();
    }
    for (int r = 0; r < 3; r++) {                      // bwd levels
        int l = 4 * r + seg;
        int v = p.cntb[l * NBLK + b];
        s[t] = v; __syncthreads();
        for (int off = 1; off < NBLK; off <<= 1) {
            int add = (b >= off) ? s[t - off] : 0; __syncthreads();
            s[t] += add; __syncthreads();
        }
        p.blkb[l * NBLK + b] = s[t] - v;
        if (b == NBLK - 1) tot[16 + l] = s[t];
        __syncthreads();
    }
    for (int r = 0; r < 4; r++) {                      // output-node batches
        int l = 4 * r + seg;
        int v = p.cnto[l * NBLK + b];
        s[t] = v; __syncthreads();
        for (int off = 1; off < NBLK; off <<= 1) {
            int add = (b >= off) ? s[t - off] : 0; __syncthreads();
            s[t] += add; __syncthreads();
        }
        p.blko[l * NBLK + b] = s[t] - v;
        if (b == NBLK - 1) tot[32 + l] = s[t];
        __syncthreads();
    }
    if (t == 0) { int a = 0; for (int l = 0; l < NLVL; l++) { meta[96 + l] = a; a += tot[l]; } meta[96 + NLVL] = a; }
    if (t == 1) { int a = 0; for (int l = 0; l < NLVL; l++) { meta[128 + l] = a; a += tot[16 + l]; } meta[128 + NLVL] = a; }
    if (t == 2) { int a = 0; for (int l = 0; l < NB; l++) { meta[160 + l] = a; a += tot[32 + l]; } meta[160 + NB] = a; }
    __syncthreads();
    for (int i = t; i < NLVL * NBLK; i += 1024) p.blkf[i] += meta[96 + (i >> 8)];
    for (int i = t; i < NLVL * NBLK; i += 1024) p.blkb[i] += meta[128 + (i >> 8)];
    for (int i = t; i < NB * NBLK; i += 1024) p.blko[i] += meta[160 + (i >> 8)];
    // bsums scan (rowptr block offsets)
    int v = (t < nblk) ? bsums[t] : 0;
    s[t] = v;
    __syncthreads();
    for (int off = 1; off < 1024; off <<= 1) {
        int add = (t >= off) ? s[t - off] : 0;
        __syncthreads();
        s[t] += add;
        __syncthreads();
    }
    if (t < nblk) bsums[t] = s[t] - v;
}

__global__ void k_scan_add(int* __restrict__ rowptr, int* __restrict__ cursor, int M, int total,
                           const int* __restrict__ bsums) {
    int g = blockIdx.x * blockDim.x + threadIdx.x;
    if (g >= M) return;
    int r = rowptr[g] + bsums[g >> 9];
    rowptr[g] = r;
    cursor[g] = r;
    if (g == 0) rowptr[M] = total;
}

// ---------------- edge scatter into CSR (high-occupancy grid-stride) --------
__global__ void k_edge_fill(Params p) {
    int g = blockIdx.x * 256 + threadIdx.x, gs = gridDim.x * 256;
    int N = p.N;
    for (int e = g; e < p.E; e += gs) {
        int s = p.src[e], d = p.dst[e];
        p.col[atomicAdd(&p.cursor[d], 1)] = s | (p.plarr[s] << 18);      // in-edge: other = src
        p.col[atomicAdd(&p.cursor[N + s], 1)] = d | (p.plarr[d] << 18);  // out-edge: other = dst
    }
}

// ---------------- node scatter from precomputed per-block bases --------------
__global__ void k_fill(Params p) {
    __shared__ int cur[48];     // fwd [0..12), bwd [16..28), out [32..48)
    int tid = threadIdx.x, bid = blockIdx.x;
    int N = p.N;
    if (tid < NLVL) { cur[tid] = p.blkf[tid * NBLK + bid]; cur[16 + tid] = p.blkb[tid * NBLK + bid]; }
    if (tid < NB) cur[32 + tid] = p.blko[tid * NBLK + bid];
    __syncthreads();
    int chunk = (N + gridDim.x - 1) / gridDim.x;
    int lo = bid * chunk, hi = lo + chunk; if (hi > N) hi = N;
    for (int i = lo + tid; i < hi; i += 256) {
        int pl = p.plarr[i];
        int lf = pl & 15, lb = (pl >> 4) & 15, tx = (pl >> 8) & 15;
        int pk = i | (pl << 18);
        p.nb_f[atomicAdd(&cur[lf], 1)] = pk;
        p.nb_b[atomicAdd(&cur[16 + lb], 1)] = pk;
        if (tx >= 3 && tx < 6)                          // nt == 1
            p.onodes[atomicAdd(&cur[32 + p.batch[i]], 1)] = pk;
    }
}

// ---------------- per-level sweep body (quarter-per-node gather + VALU matvec)
// (zero DS ops; broadcast via v_readlane — champion code, unchanged arithmetic)
template <int DIR>
__device__ __forceinline__ void sweep_level(const Params& p, int lvl,
                                            const float (&w)[64], float bv,
                                            int lane, int wid, int nw, int q, int fb) {
    const int* nb = DIR ? p.nb_b : p.nb_f;
    const int* rp = p.rowptr + (DIR ? p.N : 0);
    int start = p.meta[(DIR ? 128 : 96) + lvl];
    int cnt   = p.meta[(DIR ? 128 : 96) + lvl + 1] - start;
    float* db = DIR ? p.hB : p.hN;

    int c0 = (int)((long long)cnt * wid / nw);
    int c1 = (int)((long long)cnt * (wid + 1) / nw);
    for (int i = c0; i < c1; i += 4) {
        int my = i + q;
        int v = 0, rpv = 0, rpe = 0;
        if (my < c1) {
            int e = nb[start + my];
            v = e & 0x3FFFF;
            rpv = rp[v]; rpe = rp[v + 1];
        }
        float4 acc = make_float4(0.f, 0.f, 0.f, 0.f);
        for (int cb = rpv; cb < rpe; cb++) {
            int cu = p.col[cb];
            int u = cu & 0x3FFFF;
            int flu = (cu >> 18) & 15, blu = (cu >> 22) & 15;
            const float* sp;
            if (DIR == 0)
                sp = (flu > 0 && flu < lvl) ? (p.hN + (size_t)u * 64)
                                            : (p.tabg + ((cu >> 26) & 15) * 64);
            else
                sp = (blu > 0 && blu < lvl) ? (p.hB + (size_t)u * 64)
                   : (flu > 0)              ? (p.hN + (size_t)u * 64)
                                            : (p.tabg + ((cu >> 26) & 15) * 64);
            const float4 x = *(const float4*)(sp + fb);
            acc.x += x.x; acc.y += x.y; acc.z += x.z; acc.w += x.w;
        }
        #pragma unroll
        for (int qq = 0; qq < 4; qq++) {
            if (i + qq >= c1) break;                    // wave-uniform
            int vs   = __builtin_amdgcn_readlane(v, 16 * qq);
            int degs = __builtin_amdgcn_readlane(rpe, 16 * qq)
                     - __builtin_amdgcn_readlane(rpv, 16 * qq);
            float o = bv * (float)degs;
            #pragma unroll
            for (int m = 0; m < 16; m++) {
                float ax = rlanef(acc.x, 16 * qq + m);
                float ay = rlanef(acc.y, 16 * qq + m);
                float az = rlanef(acc.z, 16 * qq + m);
                float aw = rlanef(acc.w, 16 * qq + m);
                o = fmaf(ax, w[4 * m + 0], o);
                o = fmaf(ay, w[4 * m + 1], o);
                o = fmaf(az, w[4 * m + 2], o);
                o = fmaf(aw, w[4 * m + 3], o);
            }
            db[(size_t)vs * 64 + lane] = o;
        }
    }
}

// ---------------- fused cooperative sweep: all 22 levels, W loaded once/dir ----
__global__ __launch_bounds__(256, 4) void k_sweep_all(Params p) {
    cg::grid_group grid = cg::this_grid();
    const int tid = threadIdx.x, lane = tid & 63;
    const int wid = (blockIdx.x * 256 + tid) >> 6;
    const int nw  = (gridDim.x * 256) >> 6;
    const int q = lane >> 4, fb = (lane & 15) * 4;

    {   // forward pass
        float w[64];
        #pragma unroll
        for (int k = 0; k < 64; k++) w[k] = p.Wf[k * 64 + lane];
        float bv = p.bf[lane];
        for (int lvl = 1; lvl < NLVL; lvl++) {
            sweep_level<0>(p, lvl, w, bv, lane, wid, nw, q, fb);
            grid.sync();                                // also fences fwd->bwd
        }
    }
    {   // backward pass
        float w[64];
        #pragma unroll
        for (int k = 0; k < 64; k++) w[k] = p.Wb[k * 64 + lane];
        float bv = p.bb[lane];
        for (int lvl = 1; lvl < NLVL; lvl++) {
            sweep_level<1>(p, lvl, w, bv, lane, wid, nw, q, fb);
            if (lvl < NLVL - 1) grid.sync();            // none after last level
        }
    }
}

// ---------------- fallback per-level sweep (identical body) ------------------
__global__ __launch_bounds__(256, 4) void k_sweep(Params p, int lvl, int dir) {
    const int tid = threadIdx.x, lane = tid & 63;
    const float* W = dir ? p.Wb : p.Wf;
    float w[64];
    #pragma unroll
    for (int k = 0; k < 64; k++) w[k] = W[k * 64 + lane];
    float bv = (dir ? p.bb : p.bf)[lane];
    const int wid = (blockIdx.x * 256 + tid) >> 6;
    const int nw  = (gridDim.x * 256) >> 6;
    const int q = lane >> 4, fb = (lane & 15) * 4;
    if (dir == 0) sweep_level<0>(p, lvl, w, bv, lane, wid, nw, q, fb);
    else          sweep_level<1>(p, lvl, w, bv, lane, wid, nw, q, fb);
}

// ---------------- readout ----------------
__device__ inline void atomicMaxF(float* addr, float val) {
    int* ai = (int*)addr;
    int old = *ai;
    while (__int_as_float(old) < val) {
        int assumed = old;
        old = atomicCAS(ai, assumed, __float_as_int(val));
        if (old == assumed) break;
    }
}

__global__ void k_readout(Params p) {
    int lane = threadIdx.x & 63;
    int b = blockIdx.x >> 5;
    int sl = blockIdx.x & 31;
    int a0 = p.meta[160 + b], a1 = p.meta[161 + b];
    int cnt = a1 - a0;
    if (cnt == 0) return;
    int lo = a0 + (int)((long long)cnt * sl / 32);
    int hi = a0 + (int)((long long)cnt * (sl + 1) / 32);
    int wcnt = hi - lo;
    int wave = threadIdx.x >> 6;
    int wl = lo + (wcnt * wave) / 4;
    int wh = lo + (wcnt * (wave + 1)) / 4;
    if (wh <= wl) return;
    float mx = -FLT_MAX, sm = 0.f;
    for (int k = wl; k < wh; k += 64) {
        int take = wh - k; if (take > 64) take = 64;
        int el = (lane < take) ? p.onodes[k + lane] : 0;
        for (int j = 0; j < take; j++) {
            int e = __shfl(el, j, 64);
            int v = e & 0x3FFFF;
            int flv = (e >> 18) & 15, blv = (e >> 22) & 15;
            const float* sp = (blv > 0) ? (p.hB + (size_t)v * 64)
                            : (flv > 0) ? (p.hN + (size_t)v * 64)
                                        : (p.tabg + ((e >> 26) & 15) * 64);
            float x = sp[lane];
            mx = fmaxf(mx, x);
            sm += x;
        }
    }
    atomicMaxF(&p.out[b * 128 + lane], mx);
    atomicAdd(&p.out[b * 128 + 64 + lane], sm);
}

extern "C" void kernel_launch(void* const* d_in, const int* in_sizes, int n_in,
                              void* d_out, int out_size, void* d_ws, size_t ws_size,
                              hipStream_t stream) {
    int N = in_sizes[0];
    int E = in_sizes[2] / 2;
    int M = 2 * N;

    Params p;
    p.nt    = (const int*)d_in[0];
    p.ninv  = (const int*)d_in[1];
    p.src   = (const int*)d_in[2];
    p.dst   = (const int*)d_in[2] + E;
    p.fl    = (const int*)d_in[3];
    p.bl    = (const int*)d_in[4];
    p.batch = (const int*)d_in[5];
    p.We    = (const float*)d_in[6];
    p.be    = (const float*)d_in[7];
    p.Wf    = (const float*)d_in[8];
    p.bf    = (const float*)d_in[9];
    p.Wb    = (const float*)d_in[10];
    p.bb    = (const float*)d_in[11];
    p.out   = (float*)d_out;
    p.N = N; p.E = E; p.M = M; p.outN = out_size;

    char* ws = (char*)d_ws;
    size_t off = 0;
    auto alloc = [&](size_t bytes) -> char* {
        char* q = ws + off;
        off = (off + bytes + 255) & ~(size_t)255;
        return q;
    };
    // rowptr + meta adjacent -> one memset zeroes both
    p.rowptr = (int*)  alloc((size_t)(M + 1) * sizeof(int));
    p.meta   = (int*)  alloc(256 * sizeof(int));
    size_t zbytes = (size_t)((char*)(p.meta + 256) - (char*)p.rowptr);
    p.hN     = (float*)alloc((size_t)N * 64 * sizeof(float));
    p.hB     = (float*)alloc((size_t)N * 64 * sizeof(float));
    p.tabg   = (float*)alloc(9 * 64 * sizeof(float));
    p.cursor = (int*)  alloc((size_t)M * sizeof(int));
    p.col    = (int*)  alloc((size_t)2 * E * sizeof(int));
    p.nb_f   = (int*)  alloc((size_t)N * sizeof(int));
    p.nb_b   = (int*)  alloc((size_t)N * sizeof(int));
    p.onodes = (int*)  alloc((size_t)N * sizeof(int));
    p.plarr  = (int*)  alloc((size_t)N * sizeof(int));
    p.bsums  = (int*)  alloc(1024 * sizeof(int));
    p.cntf   = (int*)  alloc(NLVL * NBLK * sizeof(int));
    p.cntb   = (int*)  alloc(NLVL * NBLK * sizeof(int));
    p.cnto   = (int*)  alloc(NB * NBLK * sizeof(int));
    p.blkf   = (int*)  alloc(NLVL * NBLK * sizeof(int));
    p.blkb   = (int*)  alloc(NLVL * NBLK * sizeof(int));
    p.blko   = (int*)  alloc(NB * NBLK * sizeof(int));

    int nscan = (M + 511) / 512;            // 782 <= 1024

    hipMemsetAsync(p.rowptr, 0, zbytes, stream);
    k_edge_deg<<<EBLK, 256, 0, stream>>>(p);
    k_deg_hist<<<NBLK, 256, 0, stream>>>(p);
    k_scan1<<<nscan, 512, 0, stream>>>(p.rowptr, M, p.bsums);
    k_scan_top<<<1, 1024, 0, stream>>>(p.bsums, nscan, p, p.out, out_size);
    k_scan_add<<<(M + 255) / 256, 256, 0, stream>>>(p.rowptr, p.cursor, M, 2 * E, p.bsums);
    k_edge_fill<<<EBLK, 256, 0, stream>>>(p);
    k_fill<<<NBLK, 256, 0, stream>>>(p);

    void* kargs[] = { (void*)&p };
    if (hipLaunchCooperativeKernel((const void*)k_sweep_all, dim3(1024), dim3(256),
                                   kargs, 0, stream) != hipSuccess) {
        // fallback: per-level launches (identical arithmetic)
        for (int l = 1; l < NLVL; l++)
            k_sweep<<<1024, 256, 0, stream>>>(p, l, 0);
        for (int l = 1; l < NLVL; l++)
            k_sweep<<<1024, 256, 0, stream>>>(p, l, 1);
    }

    k_readout<<<NB * 32, 256, 0, stream>>>(p);
}

// Round 2
// 2826.499 us; speedup vs baseline: 1.0142x; 1.0142x over previous
//
#include <hip/hip_runtime.h>
#include <float.h>

#define NLVL 12
#define NB   16
#define NBLK 256    // blocks for deg_hist / fill node parts (per-block count arrays sized to this)
#define EBLK 2048   // blocks for edge-scatter kernels (grid-stride, no per-block state)

// meta: [96..109) base_f | [128..141) base_b | [160..177) base_o
//       [192] grid-barrier arrival counter | [208] grid-barrier generation (both zeroed by memset)
// packed entry: id(18b) | fl(4b)<<18 | bl(4b)<<22 | tidx(4b)<<26   (N=200k < 2^18)
// tidx = nt*3+ninv in 0..8 -> h_init row = tabg[tidx]  (h_init never materialized)

struct Params {
    const int *nt, *ninv, *src, *dst, *fl, *bl, *batch;
    const float *We, *be, *Wf, *bf, *Wb, *bb;
    float *hN, *hB, *tabg, *out;
    int *rowptr, *cursor, *col, *nb_f, *nb_b, *onodes, *bsums, *meta, *plarr;
    int *cntf, *cntb, *cnto, *blkf, *blkb, *blko;
    int N, E, M, outN;
};

__device__ __forceinline__ float rlanef(float x, int l) {
    return __int_as_float(__builtin_amdgcn_readlane(__float_as_int(x), l));
}

// Fully-inlined sense-reversing grid barrier. No function call -> no ABI spill of
// live registers (the cg::grid_group::sync() call demoted w[64] to scratch: VGPR 64,
// VALUBusy 3.9%, 7x regression). Agent-scope acq/rel emits buffer_wbl2/buffer_inv,
// giving cross-XCD visibility of hN/hB between levels. Requires co-residency,
// which the cooperative launch guarantees.
__device__ __forceinline__ void gbar(int* cnt, int* gen, int nblk) {
    __syncthreads();                       // drains this block's vmem before arrival
    if (threadIdx.x == 0) {
        int g = __hip_atomic_load(gen, __ATOMIC_RELAXED, __HIP_MEMORY_SCOPE_AGENT);
        int a = __hip_atomic_fetch_add(cnt, 1, __ATOMIC_ACQ_REL, __HIP_MEMORY_SCOPE_AGENT);
        if (a == nblk - 1) {
            // all arrivals done; reset counter BEFORE releasing the generation
            __hip_atomic_store(cnt, 0, __ATOMIC_RELAXED, __HIP_MEMORY_SCOPE_AGENT);
            __hip_atomic_store(gen, g + 1, __ATOMIC_RELEASE, __HIP_MEMORY_SCOPE_AGENT);
        } else {
            while (__hip_atomic_load(gen, __ATOMIC_RELAXED, __HIP_MEMORY_SCOPE_AGENT) == g)
                __builtin_amdgcn_s_sleep(8);
            (void)__hip_atomic_load(gen, __ATOMIC_ACQUIRE, __HIP_MEMORY_SCOPE_AGENT);
        }
    }
    __syncthreads();
}

// ---------------- edge-degree atomics (high-occupancy grid-stride) ----------
__global__ void k_edge_deg(Params p) {
    int g = blockIdx.x * 256 + threadIdx.x, gs = gridDim.x * 256;
    for (int e = g; e < p.E; e += gs) {
        atomicAdd(&p.rowptr[p.dst[e]], 1);
        atomicAdd(&p.rowptr[p.N + p.src[e]], 1);
    }
}

// ---------------- node histograms + packed (fl,bl,tidx) ----------------------
__global__ void k_deg_hist(Params p) {
    __shared__ int hf[NLVL], hb[NLVL], ho[NB];
    int tid = threadIdx.x, bid = blockIdx.x;
    if (tid < NLVL) { hf[tid] = 0; hb[tid] = 0; }
    if (tid < NB) ho[tid] = 0;
    __syncthreads();
    // chunk-owned nodes (same chunk map as k_fill!)
    int chunk = (p.N + gridDim.x - 1) / gridDim.x;
    int lo = bid * chunk, hi = lo + chunk; if (hi > p.N) hi = p.N;
    for (int i = lo + tid; i < hi; i += 256) {
        int f = p.fl[i], b = p.bl[i];
        int t = p.nt[i], iv = p.ninv[i];
        p.plarr[i] = f | (b << 4) | ((t * 3 + iv) << 8);
        atomicAdd(&hf[f], 1);
        atomicAdd(&hb[b], 1);
        if (t == 1) atomicAdd(&ho[p.batch[i]], 1);
    }
    __syncthreads();
    if (tid < NLVL) { p.cntf[tid * NBLK + bid] = hf[tid]; p.cntb[tid * NBLK + bid] = hb[tid]; }
    if (tid < NB) p.cnto[tid * NBLK + bid] = ho[tid];
}

// ---------------- 3-kernel exclusive scan over M = 2N ----------------
__global__ void k_scan1(int* __restrict__ data, int M, int* __restrict__ bsums) {
    __shared__ int s[512];
    int t = threadIdx.x;
    int g = blockIdx.x * 512 + t;
    int v = (g < M) ? data[g] : 0;
    s[t] = v;
    __syncthreads();
    for (int off = 1; off < 512; off <<= 1) {
        int add = (t >= off) ? s[t - off] : 0;
        __syncthreads();
        s[t] += add;
        __syncthreads();
    }
    if (g < M) data[g] = s[t] - v;
    if (t == 511) bsums[blockIdx.x] = s[511];
}

// scan_top: bsums scan + per-block-base segmented scans + meta bases + tabg + out init
__global__ void k_scan_top(int* __restrict__ bsums, int nblk, Params p,
                           float* __restrict__ out, int outN) {
    __shared__ int s[1024];
    __shared__ int tot[48];     // fwd [0..12), bwd [16..28), out [32..48)
    int t = threadIdx.x;
    int* meta = p.meta;
    for (int i = t; i < outN; i += 1024)
        out[i] = ((i & 127) < 64) ? -FLT_MAX : 0.0f;   // max-pool init == finfo.min
    if (t < 576) {              // 9-row h_init table
        int row = t >> 6, j = t & 63;
        float nf = (float)(row / 3), iv = (float)(row % 3);
        p.tabg[t] = fmaf(nf, p.We[j], fmaf(iv, p.We[64 + j], p.be[j]));
    }
    // segmented scans: 4 segments of NBLK=256 per round
    int seg = t >> 8, b = t & 255;
    for (int r = 0; r < 3; r++) {                      // fwd levels 4r+seg
        int l = 4 * r + seg;
        int v = p.cntf[l * NBLK + b];
        s[t] = v; __syncthreads();
        for (int off = 1; off < NBLK; off <<= 1) {
            int add = (b >= off) ? s[t - off] : 0; __syncthreads();
            s[t] += add; __syncthreads();
        }
        p.blkf[l * NBLK + b] = s[t] - v;
        if (b == NBLK - 1) tot[l] = s[t];
        __syncthreads();
    }
    for (int r = 0; r < 3; r++) {                      // bwd levels
        int l = 4 * r + seg;
        int v = p.cntb[l * NBLK + b];
        s[t] = v; __syncthreads();
        for (int off = 1; off < NBLK; off <<= 1) {
            int add = (b >= off) ? s[t - off] : 0; __syncthreads();
            s[t] += add; __syncthreads();
        }
        p.blkb[l * NBLK + b] = s[t] - v;
        if (b == NBLK - 1) tot[16 + l] = s[t];
        __syncthreads();
    }
    for (int r = 0; r < 4; r++) {                      // output-node batches
        int l = 4 * r + seg;
        int v = p.cnto[l * NBLK + b];
        s[t] = v; __syncthreads();
        for (int off = 1; off < NBLK; off <<= 1) {
            int add = (b >= off) ? s[t - off] : 0; __syncthreads();
            s[t] += add; __syncthreads();
        }
        p.blko[l * NBLK + b] = s[t] - v;
        if (b == NBLK - 1) tot[32 + l] = s[t];
        __syncthreads();
    }
    if (t == 0) { int a = 0; for (int l = 0; l < NLVL; l++) { meta[96 + l] = a; a += tot[l]; } meta[96 + NLVL] = a; }
    if (t == 1) { int a = 0; for (int l = 0; l < NLVL; l++) { meta[128 + l] = a; a += tot[16 + l]; } meta[128 + NLVL] = a; }
    if (t == 2) { int a = 0; for (int l = 0; l < NB; l++) { meta[160 + l] = a; a += tot[32 + l]; } meta[160 + NB] = a; }
    __syncthreads();
    for (int i = t; i < NLVL * NBLK; i += 1024) p.blkf[i] += meta[96 + (i >> 8)];
    for (int i = t; i < NLVL * NBLK; i += 1024) p.blkb[i] += meta[128 + (i >> 8)];
    for (int i = t; i < NB * NBLK; i += 1024) p.blko[i] += meta[160 + (i >> 8)];
    // bsums scan (rowptr block offsets)
    int v = (t < nblk) ? bsums[t] : 0;
    s[t] = v;
    __syncthreads();
    for (int off = 1; off < 1024; off <<= 1) {
        int add = (t >= off) ? s[t - off] : 0;
        __syncthreads();
        s[t] += add;
        __syncthreads();
    }
    if (t < nblk) bsums[t] = s[t] - v;
}

__global__ void k_scan_add(int* __restrict__ rowptr, int* __restrict__ cursor, int M, int total,
                           const int* __restrict__ bsums) {
    int g = blockIdx.x * blockDim.x + threadIdx.x;
    if (g >= M) return;
    int r = rowptr[g] + bsums[g >> 9];
    rowptr[g] = r;
    cursor[g] = r;
    if (g == 0) rowptr[M] = total;
}

// ---------------- edge scatter into CSR (high-occupancy grid-stride) --------
__global__ void k_edge_fill(Params p) {
    int g = blockIdx.x * 256 + threadIdx.x, gs = gridDim.x * 256;
    int N = p.N;
    for (int e = g; e < p.E; e += gs) {
        int s = p.src[e], d = p.dst[e];
        p.col[atomicAdd(&p.cursor[d], 1)] = s | (p.plarr[s] << 18);      // in-edge: other = src
        p.col[atomicAdd(&p.cursor[N + s], 1)] = d | (p.plarr[d] << 18);  // out-edge: other = dst
    }
}

// ---------------- node scatter from precomputed per-block bases --------------
__global__ void k_fill(Params p) {
    __shared__ int cur[48];     // fwd [0..12), bwd [16..28), out [32..48)
    int tid = threadIdx.x, bid = blockIdx.x;
    int N = p.N;
    if (tid < NLVL) { cur[tid] = p.blkf[tid * NBLK + bid]; cur[16 + tid] = p.blkb[tid * NBLK + bid]; }
    if (tid < NB) cur[32 + tid] = p.blko[tid * NBLK + bid];
    __syncthreads();
    int chunk = (N + gridDim.x - 1) / gridDim.x;
    int lo = bid * chunk, hi = lo + chunk; if (hi > N) hi = N;
    for (int i = lo + tid; i < hi; i += 256) {
        int pl = p.plarr[i];
        int lf = pl & 15, lb = (pl >> 4) & 15, tx = (pl >> 8) & 15;
        int pk = i | (pl << 18);
        p.nb_f[atomicAdd(&cur[lf], 1)] = pk;
        p.nb_b[atomicAdd(&cur[16 + lb], 1)] = pk;
        if (tx >= 3 && tx < 6)                          // nt == 1
            p.onodes[atomicAdd(&cur[32 + p.batch[i]], 1)] = pk;
    }
}

// ---------------- per-level sweep body (quarter-per-node gather + VALU matvec)
// (zero DS ops; broadcast via v_readlane — champion code, unchanged arithmetic)
template <int DIR>
__device__ __forceinline__ void sweep_level(const Params& p, int lvl,
                                            const float (&w)[64], float bv,
                                            int lane, int wid, int nw, int q, int fb) {
    const int* nb = DIR ? p.nb_b : p.nb_f;
    const int* rp = p.rowptr + (DIR ? p.N : 0);
    int start = p.meta[(DIR ? 128 : 96) + lvl];
    int cnt   = p.meta[(DIR ? 128 : 96) + lvl + 1] - start;
    float* db = DIR ? p.hB : p.hN;

    int c0 = (int)((long long)cnt * wid / nw);
    int c1 = (int)((long long)cnt * (wid + 1) / nw);
    for (int i = c0; i < c1; i += 4) {
        int my = i + q;
        int v = 0, rpv = 0, rpe = 0;
        if (my < c1) {
            int e = nb[start + my];
            v = e & 0x3FFFF;
            rpv = rp[v]; rpe = rp[v + 1];
        }
        float4 acc = make_float4(0.f, 0.f, 0.f, 0.f);
        for (int cb = rpv; cb < rpe; cb++) {
            int cu = p.col[cb];
            int u = cu & 0x3FFFF;
            int flu = (cu >> 18) & 15, blu = (cu >> 22) & 15;
            const float* sp;
            if (DIR == 0)
                sp = (flu > 0 && flu < lvl) ? (p.hN + (size_t)u * 64)
                                            : (p.tabg + ((cu >> 26) & 15) * 64);
            else
                sp = (blu > 0 && blu < lvl) ? (p.hB + (size_t)u * 64)
                   : (flu > 0)              ? (p.hN + (size_t)u * 64)
                                            : (p.tabg + ((cu >> 26) & 15) * 64);
            const float4 x = *(const float4*)(sp + fb);
            acc.x += x.x; acc.y += x.y; acc.z += x.z; acc.w += x.w;
        }
        #pragma unroll
        for (int qq = 0; qq < 4; qq++) {
            if (i + qq >= c1) break;                    // wave-uniform
            int vs   = __builtin_amdgcn_readlane(v, 16 * qq);
            int degs = __builtin_amdgcn_readlane(rpe, 16 * qq)
                     - __builtin_amdgcn_readlane(rpv, 16 * qq);
            float o = bv * (float)degs;
            #pragma unroll
            for (int m = 0; m < 16; m++) {
                float ax = rlanef(acc.x, 16 * qq + m);
                float ay = rlanef(acc.y, 16 * qq + m);
                float az = rlanef(acc.z, 16 * qq + m);
                float aw = rlanef(acc.w, 16 * qq + m);
                o = fmaf(ax, w[4 * m + 0], o);
                o = fmaf(ay, w[4 * m + 1], o);
                o = fmaf(az, w[4 * m + 2], o);
                o = fmaf(aw, w[4 * m + 3], o);
            }
            db[(size_t)vs * 64 + lane] = o;
        }
    }
}

// ---------------- fused cooperative sweep: all 22 levels, W loaded once/dir ----
// Inline manual barrier: no function call, so w[64] stays in VGPRs across levels.
__global__ __launch_bounds__(256, 4) void k_sweep_all(Params p) {
    const int tid = threadIdx.x, lane = tid & 63;
    const int wid = (blockIdx.x * 256 + tid) >> 6;
    const int nw  = (gridDim.x * 256) >> 6;
    const int q = lane >> 4, fb = (lane & 15) * 4;
    int* cnt = p.meta + 192;
    int* gen = p.meta + 208;
    const int nblk = gridDim.x;

    {   // forward pass
        float w[64];
        #pragma unroll
        for (int k = 0; k < 64; k++) w[k] = p.Wf[k * 64 + lane];
        float bv = p.bf[lane];
        for (int lvl = 1; lvl < NLVL; lvl++) {
            sweep_level<0>(p, lvl, w, bv, lane, wid, nw, q, fb);
            gbar(cnt, gen, nblk);                       // also fences fwd->bwd
        }
    }
    {   // backward pass
        float w[64];
        #pragma unroll
        for (int k = 0; k < 64; k++) w[k] = p.Wb[k * 64 + lane];
        float bv = p.bb[lane];
        for (int lvl = 1; lvl < NLVL; lvl++) {
            sweep_level<1>(p, lvl, w, bv, lane, wid, nw, q, fb);
            if (lvl < NLVL - 1) gbar(cnt, gen, nblk);   // none after last level
        }
    }
}

// ---------------- fallback per-level sweep (identical body) ------------------
__global__ __launch_bounds__(256, 4) void k_sweep(Params p, int lvl, int dir) {
    const int tid = threadIdx.x, lane = tid & 63;
    const float* W = dir ? p.Wb : p.Wf;
    float w[64];
    #pragma unroll
    for (int k = 0; k < 64; k++) w[k] = W[k * 64 + lane];
    float bv = (dir ? p.bb : p.bf)[lane];
    const int wid = (blockIdx.x * 256 + tid) >> 6;
    const int nw  = (gridDim.x * 256) >> 6;
    const int q = lane >> 4, fb = (lane & 15) * 4;
    if (dir == 0) sweep_level<0>(p, lvl, w, bv, lane, wid, nw, q, fb);
    else          sweep_level<1>(p, lvl, w, bv, lane, wid, nw, q, fb);
}

// ---------------- readout ----------------
__device__ inline void atomicMaxF(float* addr, float val) {
    int* ai = (int*)addr;
    int old = *ai;
    while (__int_as_float(old) < val) {
        int assumed = old;
        old = atomicCAS(ai, assumed, __float_as_int(val));
        if (old == assumed) break;
    }
}

__global__ void k_readout(Params p) {
    int lane = threadIdx.x & 63;
    int b = blockIdx.x >> 5;
    int sl = blockIdx.x & 31;
    int a0 = p.meta[160 + b], a1 = p.meta[161 + b];
    int cnt = a1 - a0;
    if (cnt == 0) return;
    int lo = a0 + (int)((long long)cnt * sl / 32);
    int hi = a0 + (int)((long long)cnt * (sl + 1) / 32);
    int wcnt = hi - lo;
    int wave = threadIdx.x >> 6;
    int wl = lo + (wcnt * wave) / 4;
    int wh = lo + (wcnt * (wave + 1)) / 4;
    if (wh <= wl) return;
    float mx = -FLT_MAX, sm = 0.f;
    for (int k = wl; k < wh; k += 64) {
        int take = wh - k; if (take > 64) take = 64;
        int el = (lane < take) ? p.onodes[k + lane] : 0;
        for (int j = 0; j < take; j++) {
            int e = __shfl(el, j, 64);
            int v = e & 0x3FFFF;
            int flv = (e >> 18) & 15, blv = (e >> 22) & 15;
            const float* sp = (blv > 0) ? (p.hB + (size_t)v * 64)
                            : (flv > 0) ? (p.hN + (size_t)v * 64)
                                        : (p.tabg + ((e >> 26) & 15) * 64);
            float x = sp[lane];
            mx = fmaxf(mx, x);
            sm += x;
        }
    }
    atomicMaxF(&p.out[b * 128 + lane], mx);
    atomicAdd(&p.out[b * 128 + 64 + lane], sm);
}

extern "C" void kernel_launch(void* const* d_in, const int* in_sizes, int n_in,
                              void* d_out, int out_size, void* d_ws, size_t ws_size,
                              hipStream_t stream) {
    int N = in_sizes[0];
    int E = in_sizes[2] / 2;
    int M = 2 * N;

    Params p;
    p.nt    = (const int*)d_in[0];
    p.ninv  = (const int*)d_in[1];
    p.src   = (const int*)d_in[2];
    p.dst   = (const int*)d_in[2] + E;
    p.fl    = (const int*)d_in[3];
    p.bl    = (const int*)d_in[4];
    p.batch = (const int*)d_in[5];
    p.We    = (const float*)d_in[6];
    p.be    = (const float*)d_in[7];
    p.Wf    = (const float*)d_in[8];
    p.bf    = (const float*)d_in[9];
    p.Wb    = (const float*)d_in[10];
    p.bb    = (const float*)d_in[11];
    p.out   = (float*)d_out;
    p.N = N; p.E = E; p.M = M; p.outN = out_size;

    char* ws = (char*)d_ws;
    size_t off = 0;
    auto alloc = [&](size_t bytes) -> char* {
        char* q = ws + off;
        off = (off + bytes + 255) & ~(size_t)255;
        return q;
    };
    // rowptr + meta adjacent -> one memset zeroes both (incl. barrier cnt/gen)
    p.rowptr = (int*)  alloc((size_t)(M + 1) * sizeof(int));
    p.meta   = (int*)  alloc(256 * sizeof(int));
    size_t zbytes = (size_t)((char*)(p.meta + 256) - (char*)p.rowptr);
    p.hN     = (float*)alloc((size_t)N * 64 * sizeof(float));
    p.hB     = (float*)alloc((size_t)N * 64 * sizeof(float));
    p.tabg   = (float*)alloc(9 * 64 * sizeof(float));
    p.cursor = (int*)  alloc((size_t)M * sizeof(int));
    p.col    = (int*)  alloc((size_t)2 * E * sizeof(int));
    p.nb_f   = (int*)  alloc((size_t)N * sizeof(int));
    p.nb_b   = (int*)  alloc((size_t)N * sizeof(int));
    p.onodes = (int*)  alloc((size_t)N * sizeof(int));
    p.plarr  = (int*)  alloc((size_t)N * sizeof(int));
    p.bsums  = (int*)  alloc(1024 * sizeof(int));
    p.cntf   = (int*)  alloc(NLVL * NBLK * sizeof(int));
    p.cntb   = (int*)  alloc(NLVL * NBLK * sizeof(int));
    p.cnto   = (int*)  alloc(NB * NBLK * sizeof(int));
    p.blkf   = (int*)  alloc(NLVL * NBLK * sizeof(int));
    p.blkb   = (int*)  alloc(NLVL * NBLK * sizeof(int));
    p.blko   = (int*)  alloc(NB * NBLK * sizeof(int));

    int nscan = (M + 511) / 512;            // 782 <= 1024

    hipMemsetAsync(p.rowptr, 0, zbytes, stream);
    k_edge_deg<<<EBLK, 256, 0, stream>>>(p);
    k_deg_hist<<<NBLK, 256, 0, stream>>>(p);
    k_scan1<<<nscan, 512, 0, stream>>>(p.rowptr, M, p.bsums);
    k_scan_top<<<1, 1024, 0, stream>>>(p.bsums, nscan, p, p.out, out_size);
    k_scan_add<<<(M + 255) / 256, 256, 0, stream>>>(p.rowptr, p.cursor, M, 2 * E, p.bsums);
    k_edge_fill<<<EBLK, 256, 0, stream>>>(p);
    k_fill<<<NBLK, 256, 0, stream>>>(p);

    void* kargs[] = { (void*)&p };
    if (hipLaunchCooperativeKernel((const void*)k_sweep_all, dim3(1024), dim3(256),
                                   kargs, 0, stream) != hipSuccess) {
        // fallback: per-level launches (identical arithmetic)
        for (int l = 1; l < NLVL; l++)
            k_sweep<<<1024, 256, 0, stream>>>(p, l, 0);
        for (int l = 1; l < NLVL; l++)
            k_sweep<<<1024, 256, 0, stream>>>(p, l, 1);
    }

    k_readout<<<NB * 32, 256, 0, stream>>>(p);
}

// Round 3
// 783.439 us; speedup vs baseline: 3.6590x; 3.6078x over previous
//
#include <hip/hip_runtime.h>
#include <float.h>

#define NLVL 12
#define NB   16
#define NBLK 256    // blocks for deg_hist / fill node parts (per-block count arrays sized to this)
#define EBLK 2048   // blocks for edge-scatter kernels (grid-stride, no per-block state)
#define SWBLK 1024  // cooperative sweep grid (4 blocks/CU x 256 CU)

// meta: [96..109) base_f | [128..141) base_b | [160..177) base_o
//       [256 + 32*i], i=0..15 : grid-barrier sub-counters (one 128B line each; zeroed by memset)
// packed entry: id(18b) | fl(4b)<<18 | bl(4b)<<22 | tidx(4b)<<26   (N=200k < 2^18)
// tidx = nt*3+ninv in 0..8 -> h_init row = tabg[tidx]  (h_init never materialized)

struct Params {
    const int *nt, *ninv, *src, *dst, *fl, *bl, *batch;
    const float *We, *be, *Wf, *bf, *Wb, *bb;
    float *hN, *hB, *tabg, *out;
    int *rowptr, *cursor, *col, *nb_f, *nb_b, *onodes, *bsums, *meta, *plarr;
    int *cntf, *cntb, *cnto, *blkf, *blkb, *blko;
    int N, E, M, outN;
};

__device__ __forceinline__ float rlanef(float x, int l) {
    return __int_as_float(__builtin_amdgcn_readlane(__float_as_int(x), l));
}

// Maintenance-free grid barrier (monotone, no reset, no fences):
//  - h-stores in the sweep are agent-scope relaxed atomic stores (write-through to the
//    coherence point), so NO buffer_wbl2 is needed at release time.
//  - every h row is single-writer-once and only read after its write, and kernel-launch
//    acquire covers prior-run staleness, so NO buffer_inv is needed at acquire time.
//    (rounds 1/2: per-block wbl2/inv from acq_rel semantics ~= 100us/barrier -> 2.4ms.)
//  - arrivals spread over 16 cache-line-spaced sub-counters; waiter polls the sum until
//    it reaches nblk*t (t = barrier ordinal), so successive barriers need no reset.
__device__ __forceinline__ void gbar2(int* subs, int nblk, int t) {
    __syncthreads();                      // emits s_waitcnt vmcnt(0): sc1 stores at MALL
    if (threadIdx.x == 0) {
        __hip_atomic_fetch_add(&subs[(blockIdx.x & 15) * 32], 1,
                               __ATOMIC_RELAXED, __HIP_MEMORY_SCOPE_AGENT);
        const int target = nblk * t;
        for (;;) {
            int s = 0;
            #pragma unroll
            for (int i = 0; i < 16; i++)
                s += __hip_atomic_load(&subs[i * 32], __ATOMIC_RELAXED,
                                       __HIP_MEMORY_SCOPE_AGENT);
            if (s >= target) break;
            __builtin_amdgcn_s_sleep(16);
        }
    }
    asm volatile("" ::: "memory");        // compiler fence: no load motion across the wait
    __syncthreads();
}

// ---------------- edge-degree atomics (high-occupancy grid-stride) ----------
__global__ void k_edge_deg(Params p) {
    int g = blockIdx.x * 256 + threadIdx.x, gs = gridDim.x * 256;
    for (int e = g; e < p.E; e += gs) {
        atomicAdd(&p.rowptr[p.dst[e]], 1);
        atomicAdd(&p.rowptr[p.N + p.src[e]], 1);
    }
}

// ---------------- node histograms + packed (fl,bl,tidx) ----------------------
__global__ void k_deg_hist(Params p) {
    __shared__ int hf[NLVL], hb[NLVL], ho[NB];
    int tid = threadIdx.x, bid = blockIdx.x;
    if (tid < NLVL) { hf[tid] = 0; hb[tid] = 0; }
    if (tid < NB) ho[tid] = 0;
    __syncthreads();
    // chunk-owned nodes (same chunk map as k_fill!)
    int chunk = (p.N + gridDim.x - 1) / gridDim.x;
    int lo = bid * chunk, hi = lo + chunk; if (hi > p.N) hi = p.N;
    for (int i = lo + tid; i < hi; i += 256) {
        int f = p.fl[i], b = p.bl[i];
        int t = p.nt[i], iv = p.ninv[i];
        p.plarr[i] = f | (b << 4) | ((t * 3 + iv) << 8);
        atomicAdd(&hf[f], 1);
        atomicAdd(&hb[b], 1);
        if (t == 1) atomicAdd(&ho[p.batch[i]], 1);
    }
    __syncthreads();
    if (tid < NLVL) { p.cntf[tid * NBLK + bid] = hf[tid]; p.cntb[tid * NBLK + bid] = hb[tid]; }
    if (tid < NB) p.cnto[tid * NBLK + bid] = ho[tid];
}

// ---------------- 3-kernel exclusive scan over M = 2N ----------------
__global__ void k_scan1(int* __restrict__ data, int M, int* __restrict__ bsums) {
    __shared__ int s[512];
    int t = threadIdx.x;
    int g = blockIdx.x * 512 + t;
    int v = (g < M) ? data[g] : 0;
    s[t] = v;
    __syncthreads();
    for (int off = 1; off < 512; off <<= 1) {
        int add = (t >= off) ? s[t - off] : 0;
        __syncthreads();
        s[t] += add;
        __syncthreads();
    }
    if (g < M) data[g] = s[t] - v;
    if (t == 511) bsums[blockIdx.x] = s[511];
}

// scan_top: bsums scan + per-block-base segmented scans + meta bases + tabg + out init
__global__ void k_scan_top(int* __restrict__ bsums, int nblk, Params p,
                           float* __restrict__ out, int outN) {
    __shared__ int s[1024];
    __shared__ int tot[48];     // fwd [0..12), bwd [16..28), out [32..48)
    int t = threadIdx.x;
    int* meta = p.meta;
    for (int i = t; i < outN; i += 1024)
        out[i] = ((i & 127) < 64) ? -FLT_MAX : 0.0f;   // max-pool init == finfo.min
    if (t < 576) {              // 9-row h_init table
        int row = t >> 6, j = t & 63;
        float nf = (float)(row / 3), iv = (float)(row % 3);
        p.tabg[t] = fmaf(nf, p.We[j], fmaf(iv, p.We[64 + j], p.be[j]));
    }
    // segmented scans: 4 segments of NBLK=256 per round
    int seg = t >> 8, b = t & 255;
    for (int r = 0; r < 3; r++) {                      // fwd levels 4r+seg
        int l = 4 * r + seg;
        int v = p.cntf[l * NBLK + b];
        s[t] = v; __syncthreads();
        for (int off = 1; off < NBLK; off <<= 1) {
            int add = (b >= off) ? s[t - off] : 0; __syncthreads();
            s[t] += add; __syncthreads();
        }
        p.blkf[l * NBLK + b] = s[t] - v;
        if (b == NBLK - 1) tot[l] = s[t];
        __syncthreads();
    }
    for (int r = 0; r < 3; r++) {                      // bwd levels
        int l = 4 * r + seg;
        int v = p.cntb[l * NBLK + b];
        s[t] = v; __syncthreads();
        for (int off = 1; off < NBLK; off <<= 1) {
            int add = (b >= off) ? s[t - off] : 0; __syncthreads();
            s[t] += add; __syncthreads();
        }
        p.blkb[l * NBLK + b] = s[t] - v;
        if (b == NBLK - 1) tot[16 + l] = s[t];
        __syncthreads();
    }
    for (int r = 0; r < 4; r++) {                      // output-node batches
        int l = 4 * r + seg;
        int v = p.cnto[l * NBLK + b];
        s[t] = v; __syncthreads();
        for (int off = 1; off < NBLK; off <<= 1) {
            int add = (b >= off) ? s[t - off] : 0; __syncthreads();
            s[t] += add; __syncthreads();
        }
        p.blko[l * NBLK + b] = s[t] - v;
        if (b == NBLK - 1) tot[32 + l] = s[t];
        __syncthreads();
    }
    if (t == 0) { int a = 0; for (int l = 0; l < NLVL; l++) { meta[96 + l] = a; a += tot[l]; } meta[96 + NLVL] = a; }
    if (t == 1) { int a = 0; for (int l = 0; l < NLVL; l++) { meta[128 + l] = a; a += tot[16 + l]; } meta[128 + NLVL] = a; }
    if (t == 2) { int a = 0; for (int l = 0; l < NB; l++) { meta[160 + l] = a; a += tot[32 + l]; } meta[160 + NB] = a; }
    __syncthreads();
    for (int i = t; i < NLVL * NBLK; i += 1024) p.blkf[i] += meta[96 + (i >> 8)];
    for (int i = t; i < NLVL * NBLK; i += 1024) p.blkb[i] += meta[128 + (i >> 8)];
    for (int i = t; i < NB * NBLK; i += 1024) p.blko[i] += meta[160 + (i >> 8)];
    // bsums scan (rowptr block offsets)
    int v = (t < nblk) ? bsums[t] : 0;
    s[t] = v;
    __syncthreads();
    for (int off = 1; off < 1024; off <<= 1) {
        int add = (t >= off) ? s[t - off] : 0;
        __syncthreads();
        s[t] += add;
        __syncthreads();
    }
    if (t < nblk) bsums[t] = s[t] - v;
}

__global__ void k_scan_add(int* __restrict__ rowptr, int* __restrict__ cursor, int M, int total,
                           const int* __restrict__ bsums) {
    int g = blockIdx.x * blockDim.x + threadIdx.x;
    if (g >= M) return;
    int r = rowptr[g] + bsums[g >> 9];
    rowptr[g] = r;
    cursor[g] = r;
    if (g == 0) rowptr[M] = total;
}

// ---------------- edge scatter into CSR (high-occupancy grid-stride) --------
__global__ void k_edge_fill(Params p) {
    int g = blockIdx.x * 256 + threadIdx.x, gs = gridDim.x * 256;
    int N = p.N;
    for (int e = g; e < p.E; e += gs) {
        int s = p.src[e], d = p.dst[e];
        p.col[atomicAdd(&p.cursor[d], 1)] = s | (p.plarr[s] << 18);      // in-edge: other = src
        p.col[atomicAdd(&p.cursor[N + s], 1)] = d | (p.plarr[d] << 18);  // out-edge: other = dst
    }
}

// ---------------- node scatter from precomputed per-block bases --------------
__global__ void k_fill(Params p) {
    __shared__ int cur[48];     // fwd [0..12), bwd [16..28), out [32..48)
    int tid = threadIdx.x, bid = blockIdx.x;
    int N = p.N;
    if (tid < NLVL) { cur[tid] = p.blkf[tid * NBLK + bid]; cur[16 + tid] = p.blkb[tid * NBLK + bid]; }
    if (tid < NB) cur[32 + tid] = p.blko[tid * NBLK + bid];
    __syncthreads();
    int chunk = (N + gridDim.x - 1) / gridDim.x;
    int lo = bid * chunk, hi = lo + chunk; if (hi > N) hi = N;
    for (int i = lo + tid; i < hi; i += 256) {
        int pl = p.plarr[i];
        int lf = pl & 15, lb = (pl >> 4) & 15, tx = (pl >> 8) & 15;
        int pk = i | (pl << 18);
        p.nb_f[atomicAdd(&cur[lf], 1)] = pk;
        p.nb_b[atomicAdd(&cur[16 + lb], 1)] = pk;
        if (tx >= 3 && tx < 6)                          // nt == 1
            p.onodes[atomicAdd(&cur[32 + p.batch[i]], 1)] = pk;
    }
}

// ---------------- per-level sweep body (quarter-per-node gather + VALU matvec)
// (zero DS ops; broadcast via v_readlane — champion code; h-store is now an
// agent-scope relaxed atomic store = write-through to the coherence point)
template <int DIR>
__device__ __forceinline__ void sweep_level(const Params& p, int lvl,
                                            const float (&w)[64], float bv,
                                            int lane, int wid, int nw, int q, int fb) {
    const int* nb = DIR ? p.nb_b : p.nb_f;
    const int* rp = p.rowptr + (DIR ? p.N : 0);
    int start = p.meta[(DIR ? 128 : 96) + lvl];
    int cnt   = p.meta[(DIR ? 128 : 96) + lvl + 1] - start;
    float* db = DIR ? p.hB : p.hN;

    int c0 = (int)((long long)cnt * wid / nw);
    int c1 = (int)((long long)cnt * (wid + 1) / nw);
    for (int i = c0; i < c1; i += 4) {
        int my = i + q;
        int v = 0, rpv = 0, rpe = 0;
        if (my < c1) {
            int e = nb[start + my];
            v = e & 0x3FFFF;
            rpv = rp[v]; rpe = rp[v + 1];
        }
        float4 acc = make_float4(0.f, 0.f, 0.f, 0.f);
        for (int cb = rpv; cb < rpe; cb++) {
            int cu = p.col[cb];
            int u = cu & 0x3FFFF;
            int flu = (cu >> 18) & 15, blu = (cu >> 22) & 15;
            const float* sp;
            if (DIR == 0)
                sp = (flu > 0 && flu < lvl) ? (p.hN + (size_t)u * 64)
                                            : (p.tabg + ((cu >> 26) & 15) * 64);
            else
                sp = (blu > 0 && blu < lvl) ? (p.hB + (size_t)u * 64)
                   : (flu > 0)              ? (p.hN + (size_t)u * 64)
                                            : (p.tabg + ((cu >> 26) & 15) * 64);
            const float4 x = *(const float4*)(sp + fb);
            acc.x += x.x; acc.y += x.y; acc.z += x.z; acc.w += x.w;
        }
        #pragma unroll
        for (int qq = 0; qq < 4; qq++) {
            if (i + qq >= c1) break;                    // wave-uniform
            int vs   = __builtin_amdgcn_readlane(v, 16 * qq);
            int degs = __builtin_amdgcn_readlane(rpe, 16 * qq)
                     - __builtin_amdgcn_readlane(rpv, 16 * qq);
            float o = bv * (float)degs;
            #pragma unroll
            for (int m = 0; m < 16; m++) {
                float ax = rlanef(acc.x, 16 * qq + m);
                float ay = rlanef(acc.y, 16 * qq + m);
                float az = rlanef(acc.z, 16 * qq + m);
                float aw = rlanef(acc.w, 16 * qq + m);
                o = fmaf(ax, w[4 * m + 0], o);
                o = fmaf(ay, w[4 * m + 1], o);
                o = fmaf(az, w[4 * m + 2], o);
                o = fmaf(aw, w[4 * m + 3], o);
            }
            // write-through to coherence point: makes the row agent-visible once
            // vmcnt drains (at the next __syncthreads), so the barrier needs no wbl2
            __hip_atomic_store(&db[(size_t)vs * 64 + lane], o,
                               __ATOMIC_RELAXED, __HIP_MEMORY_SCOPE_AGENT);
        }
    }
}

// ---------------- fused cooperative sweep: all 22 levels, W loaded once/dir ----
// amdgpu_waves_per_eu(4,4): pin occupancy target so the allocator gets the full
// 128-VGPR budget and keeps w[64] resident (rounds 1/2 squeezed to 64 VGPR = scratch).
__global__ __launch_bounds__(256) __attribute__((amdgpu_waves_per_eu(4, 4)))
void k_sweep_all(Params p) {
    const int tid = threadIdx.x, lane = tid & 63;
    const int wid = (blockIdx.x * 256 + tid) >> 6;
    const int nw  = (gridDim.x * 256) >> 6;
    const int q = lane >> 4, fb = (lane & 15) * 4;
    int* subs = p.meta + 256;
    const int nblk = gridDim.x;
    int t = 0;

    {   // forward pass
        float w[64];
        #pragma unroll
        for (int k = 0; k < 64; k++) w[k] = p.Wf[k * 64 + lane];
        float bv = p.bf[lane];
        for (int lvl = 1; lvl < NLVL; lvl++) {
            sweep_level<0>(p, lvl, w, bv, lane, wid, nw, q, fb);
            gbar2(subs, nblk, ++t);                     // also fences fwd->bwd
        }
    }
    {   // backward pass
        float w[64];
        #pragma unroll
        for (int k = 0; k < 64; k++) w[k] = p.Wb[k * 64 + lane];
        float bv = p.bb[lane];
        for (int lvl = 1; lvl < NLVL; lvl++) {
            sweep_level<1>(p, lvl, w, bv, lane, wid, nw, q, fb);
            if (lvl < NLVL - 1) gbar2(subs, nblk, ++t); // none after last level
        }
    }
}

// ---------------- fallback per-level sweep (identical body) ------------------
__global__ __launch_bounds__(256) __attribute__((amdgpu_waves_per_eu(4, 4)))
void k_sweep(Params p, int lvl, int dir) {
    const int tid = threadIdx.x, lane = tid & 63;
    const float* W = dir ? p.Wb : p.Wf;
    float w[64];
    #pragma unroll
    for (int k = 0; k < 64; k++) w[k] = W[k * 64 + lane];
    float bv = (dir ? p.bb : p.bf)[lane];
    const int wid = (blockIdx.x * 256 + tid) >> 6;
    const int nw  = (gridDim.x * 256) >> 6;
    const int q = lane >> 4, fb = (lane & 15) * 4;
    if (dir == 0) sweep_level<0>(p, lvl, w, bv, lane, wid, nw, q, fb);
    else          sweep_level<1>(p, lvl, w, bv, lane, wid, nw, q, fb);
}

// ---------------- readout ----------------
__device__ inline void atomicMaxF(float* addr, float val) {
    int* ai = (int*)addr;
    int old = *ai;
    while (__int_as_float(old) < val) {
        int assumed = old;
        old = atomicCAS(ai, assumed, __float_as_int(val));
        if (old == assumed) break;
    }
}

__global__ void k_readout(Params p) {
    int lane = threadIdx.x & 63;
    int b = blockIdx.x >> 5;
    int sl = blockIdx.x & 31;
    int a0 = p.meta[160 + b], a1 = p.meta[161 + b];
    int cnt = a1 - a0;
    if (cnt == 0) return;
    int lo = a0 + (int)((long long)cnt * sl / 32);
    int hi = a0 + (int)((long long)cnt * (sl + 1) / 32);
    int wcnt = hi - lo;
    int wave = threadIdx.x >> 6;
    int wl = lo + (wcnt * wave) / 4;
    int wh = lo + (wcnt * (wave + 1)) / 4;
    if (wh <= wl) return;
    float mx = -FLT_MAX, sm = 0.f;
    for (int k = wl; k < wh; k += 64) {
        int take = wh - k; if (take > 64) take = 64;
        int el = (lane < take) ? p.onodes[k + lane] : 0;
        for (int j = 0; j < take; j++) {
            int e = __shfl(el, j, 64);
            int v = e & 0x3FFFF;
            int flv = (e >> 18) & 15, blv = (e >> 22) & 15;
            const float* sp = (blv > 0) ? (p.hB + (size_t)v * 64)
                            : (flv > 0) ? (p.hN + (size_t)v * 64)
                                        : (p.tabg + ((e >> 26) & 15) * 64);
            float x = sp[lane];
            mx = fmaxf(mx, x);
            sm += x;
        }
    }
    atomicMaxF(&p.out[b * 128 + lane], mx);
    atomicAdd(&p.out[b * 128 + 64 + lane], sm);
}

extern "C" void kernel_launch(void* const* d_in, const int* in_sizes, int n_in,
                              void* d_out, int out_size, void* d_ws, size_t ws_size,
                              hipStream_t stream) {
    int N = in_sizes[0];
    int E = in_sizes[2] / 2;
    int M = 2 * N;

    Params p;
    p.nt    = (const int*)d_in[0];
    p.ninv  = (const int*)d_in[1];
    p.src   = (const int*)d_in[2];
    p.dst   = (const int*)d_in[2] + E;
    p.fl    = (const int*)d_in[3];
    p.bl    = (const int*)d_in[4];
    p.batch = (const int*)d_in[5];
    p.We    = (const float*)d_in[6];
    p.be    = (const float*)d_in[7];
    p.Wf    = (const float*)d_in[8];
    p.bf    = (const float*)d_in[9];
    p.Wb    = (const float*)d_in[10];
    p.bb    = (const float*)d_in[11];
    p.out   = (float*)d_out;
    p.N = N; p.E = E; p.M = M; p.outN = out_size;

    char* ws = (char*)d_ws;
    size_t off = 0;
    auto alloc = [&](size_t bytes) -> char* {
        char* q = ws + off;
        off = (off + bytes + 255) & ~(size_t)255;
        return q;
    };
    // rowptr + meta adjacent -> one memset zeroes both (incl. barrier sub-counters)
    p.rowptr = (int*)  alloc((size_t)(M + 1) * sizeof(int));
    p.meta   = (int*)  alloc(1024 * sizeof(int));
    size_t zbytes = (size_t)((char*)(p.meta + 1024) - (char*)p.rowptr);
    p.hN     = (float*)alloc((size_t)N * 64 * sizeof(float));
    p.hB     = (float*)alloc((size_t)N * 64 * sizeof(float));
    p.tabg   = (float*)alloc(9 * 64 * sizeof(float));
    p.cursor = (int*)  alloc((size_t)M * sizeof(int));
    p.col    = (int*)  alloc((size_t)2 * E * sizeof(int));
    p.nb_f   = (int*)  alloc((size_t)N * sizeof(int));
    p.nb_b   = (int*)  alloc((size_t)N * sizeof(int));
    p.onodes = (int*)  alloc((size_t)N * sizeof(int));
    p.plarr  = (int*)  alloc((size_t)N * sizeof(int));
    p.bsums  = (int*)  alloc(1024 * sizeof(int));
    p.cntf   = (int*)  alloc(NLVL * NBLK * sizeof(int));
    p.cntb   = (int*)  alloc(NLVL * NBLK * sizeof(int));
    p.cnto   = (int*)  alloc(NB * NBLK * sizeof(int));
    p.blkf   = (int*)  alloc(NLVL * NBLK * sizeof(int));
    p.blkb   = (int*)  alloc(NLVL * NBLK * sizeof(int));
    p.blko   = (int*)  alloc(NB * NBLK * sizeof(int));

    int nscan = (M + 511) / 512;            // 782 <= 1024

    hipMemsetAsync(p.rowptr, 0, zbytes, stream);
    k_edge_deg<<<EBLK, 256, 0, stream>>>(p);
    k_deg_hist<<<NBLK, 256, 0, stream>>>(p);
    k_scan1<<<nscan, 512, 0, stream>>>(p.rowptr, M, p.bsums);
    k_scan_top<<<1, 1024, 0, stream>>>(p.bsums, nscan, p, p.out, out_size);
    k_scan_add<<<(M + 255) / 256, 256, 0, stream>>>(p.rowptr, p.cursor, M, 2 * E, p.bsums);
    k_edge_fill<<<EBLK, 256, 0, stream>>>(p);
    k_fill<<<NBLK, 256, 0, stream>>>(p);

    void* kargs[] = { (void*)&p };
    if (hipLaunchCooperativeKernel((const void*)k_sweep_all, dim3(SWBLK), dim3(256),
                                   kargs, 0, stream) != hipSuccess) {
        // fallback: per-level launches (identical arithmetic)
        for (int l = 1; l < NLVL; l++)
            k_sweep<<<1024, 256, 0, stream>>>(p, l, 0);
        for (int l = 1; l < NLVL; l++)
            k_sweep<<<1024, 256, 0, stream>>>(p, l, 1);
    }

    k_readout<<<NB * 32, 256, 0, stream>>>(p);
}

// Round 4
// 559.960 us; speedup vs baseline: 5.1193x; 1.3991x over previous
//
#include <hip/hip_runtime.h>
#include <float.h>

#define NLVL 12
#define NB   16
#define NBLK 256    // blocks for deg_hist / fill node parts (per-block count arrays sized to this)
#define EBLK 2048   // blocks for edge-scatter kernels (grid-stride, no per-block state)
#define SWBLK 1024  // max cooperative sweep grid (4 blocks/CU x 256 CU)

// meta: [96..109) base_f | [128..141) base_b | [160..177) base_o
// bar (128B lines): [0..16) arrival sub-counters | 16 master | 17 master-release |
//                   [18..18+nblk) per-block release flags  (all monotone; zeroed per launch)
// packed entry: id(18b) | fl(4b)<<18 | bl(4b)<<22 | tidx(4b)<<26   (N=200k < 2^18)
// tidx = nt*3+ninv in 0..8 -> h_init row = tabg[tidx]  (h_init never materialized)

struct Params {
    const int *nt, *ninv, *src, *dst, *fl, *bl, *batch;
    const float *We, *be, *Wf, *bf, *Wb, *bb;
    float *hN, *hB, *tabg, *out;
    int *rowptr, *cursor, *col, *nb_f, *nb_b, *onodes, *bsums, *meta, *plarr, *bar;
    int *cntf, *cntb, *cnto, *blkf, *blkb, *blko;
    int N, E, M, outN;
};

__device__ __forceinline__ float rlanef(float x, int l) {
    return __int_as_float(__builtin_amdgcn_readlane(__float_as_int(x), l));
}

// Hierarchical maintenance-free grid barrier (monotone, no fences, no wbl2/inv).
// Round-3's flat poll (1024 blocks x 16 shared lines) serialized at the MALL
// (~15us/barrier). Here: arrivals on 16 spread lines; last-on-line = captain ->
// master counter; last captain stores master-release; captains fan the epoch out
// to PER-BLOCK private flag lines; each block polls only its own line.
// h-visibility needs no cache maintenance: h-stores are agent-scope write-through
// (sc1) drained by the vmcnt(0) in __syncthreads BEFORE the arrival add, and no
// h row is ever demand-fetched by any cache before it is written (single-writer-
// once dataflow; rows are 256B line-aligned so no false sharing).
__device__ __forceinline__ void gbar3(int* bar, int nblk, int t) {
    __syncthreads();                       // vmcnt(0): h-stores at coherence point
    if (threadIdx.x == 0) {
        const int line = blockIdx.x & 15;
        const int per  = nblk >> 4;        // blocks per line (nblk multiple of 16)
        int a = __hip_atomic_fetch_add(&bar[line * 32], 1,
                                       __ATOMIC_RELAXED, __HIP_MEMORY_SCOPE_AGENT);
        if (a == per * t - 1) {            // captain: last arrival on this line
            int m = __hip_atomic_fetch_add(&bar[16 * 32], 1,
                                           __ATOMIC_RELAXED, __HIP_MEMORY_SCOPE_AGENT);
            if (m == 16 * t - 1) {         // last captain overall -> release
                __hip_atomic_store(&bar[17 * 32], t,
                                   __ATOMIC_RELAXED, __HIP_MEMORY_SCOPE_AGENT);
            } else {
                while (__hip_atomic_load(&bar[17 * 32], __ATOMIC_RELAXED,
                                         __HIP_MEMORY_SCOPE_AGENT) < t)
                    __builtin_amdgcn_s_sleep(1);
            }
            for (int b = line; b < nblk; b += 16)   // fan-out to my blocks
                __hip_atomic_store(&bar[(18 + b) * 32], t,
                                   __ATOMIC_RELAXED, __HIP_MEMORY_SCOPE_AGENT);
        } else {
            while (__hip_atomic_load(&bar[(18 + blockIdx.x) * 32], __ATOMIC_RELAXED,
                                     __HIP_MEMORY_SCOPE_AGENT) < t)
                __builtin_amdgcn_s_sleep(4);
        }
    }
    asm volatile("" ::: "memory");         // no load motion across the wait
    __syncthreads();
}

// ---------------- edge-degree atomics (high-occupancy grid-stride) ----------
__global__ void k_edge_deg(Params p) {
    int g = blockIdx.x * 256 + threadIdx.x, gs = gridDim.x * 256;
    for (int e = g; e < p.E; e += gs) {
        atomicAdd(&p.rowptr[p.dst[e]], 1);
        atomicAdd(&p.rowptr[p.N + p.src[e]], 1);
    }
}

// ---------------- node histograms + packed (fl,bl,tidx) ----------------------
__global__ void k_deg_hist(Params p) {
    __shared__ int hf[NLVL], hb[NLVL], ho[NB];
    int tid = threadIdx.x, bid = blockIdx.x;
    if (tid < NLVL) { hf[tid] = 0; hb[tid] = 0; }
    if (tid < NB) ho[tid] = 0;
    __syncthreads();
    // chunk-owned nodes (same chunk map as k_fill!)
    int chunk = (p.N + gridDim.x - 1) / gridDim.x;
    int lo = bid * chunk, hi = lo + chunk; if (hi > p.N) hi = p.N;
    for (int i = lo + tid; i < hi; i += 256) {
        int f = p.fl[i], b = p.bl[i];
        int t = p.nt[i], iv = p.ninv[i];
        p.plarr[i] = f | (b << 4) | ((t * 3 + iv) << 8);
        atomicAdd(&hf[f], 1);
        atomicAdd(&hb[b], 1);
        if (t == 1) atomicAdd(&ho[p.batch[i]], 1);
    }
    __syncthreads();
    if (tid < NLVL) { p.cntf[tid * NBLK + bid] = hf[tid]; p.cntb[tid * NBLK + bid] = hb[tid]; }
    if (tid < NB) p.cnto[tid * NBLK + bid] = ho[tid];
}

// ---------------- 3-kernel exclusive scan over M = 2N ----------------
__global__ void k_scan1(int* __restrict__ data, int M, int* __restrict__ bsums) {
    __shared__ int s[512];
    int t = threadIdx.x;
    int g = blockIdx.x * 512 + t;
    int v = (g < M) ? data[g] : 0;
    s[t] = v;
    __syncthreads();
    for (int off = 1; off < 512; off <<= 1) {
        int add = (t >= off) ? s[t - off] : 0;
        __syncthreads();
        s[t] += add;
        __syncthreads();
    }
    if (g < M) data[g] = s[t] - v;
    if (t == 511) bsums[blockIdx.x] = s[511];
}

// scan_top: bsums scan + per-block-base segmented scans + meta bases + tabg + out init
__global__ void k_scan_top(int* __restrict__ bsums, int nblk, Params p,
                           float* __restrict__ out, int outN) {
    __shared__ int s[1024];
    __shared__ int tot[48];     // fwd [0..12), bwd [16..28), out [32..48)
    int t = threadIdx.x;
    int* meta = p.meta;
    for (int i = t; i < outN; i += 1024)
        out[i] = ((i & 127) < 64) ? -FLT_MAX : 0.0f;   // max-pool init == finfo.min
    if (t < 576) {              // 9-row h_init table
        int row = t >> 6, j = t & 63;
        float nf = (float)(row / 3), iv = (float)(row % 3);
        p.tabg[t] = fmaf(nf, p.We[j], fmaf(iv, p.We[64 + j], p.be[j]));
    }
    // segmented scans: 4 segments of NBLK=256 per round
    int seg = t >> 8, b = t & 255;
    for (int r = 0; r < 3; r++) {                      // fwd levels 4r+seg
        int l = 4 * r + seg;
        int v = p.cntf[l * NBLK + b];
        s[t] = v; __syncthreads();
        for (int off = 1; off < NBLK; off <<= 1) {
            int add = (b >= off) ? s[t - off] : 0; __syncthreads();
            s[t] += add; __syncthreads();
        }
        p.blkf[l * NBLK + b] = s[t] - v;
        if (b == NBLK - 1) tot[l] = s[t];
        __syncthreads();
    }
    for (int r = 0; r < 3; r++) {                      // bwd levels
        int l = 4 * r + seg;
        int v = p.cntb[l * NBLK + b];
        s[t] = v; __syncthreads();
        for (int off = 1; off < NBLK; off <<= 1) {
            int add = (b >= off) ? s[t - off] : 0; __syncthreads();
            s[t] += add; __syncthreads();
        }
        p.blkb[l * NBLK + b] = s[t] - v;
        if (b == NBLK - 1) tot[16 + l] = s[t];
        __syncthreads();
    }
    for (int r = 0; r < 4; r++) {                      // output-node batches
        int l = 4 * r + seg;
        int v = p.cnto[l * NBLK + b];
        s[t] = v; __syncthreads();
        for (int off = 1; off < NBLK; off <<= 1) {
            int add = (b >= off) ? s[t - off] : 0; __syncthreads();
            s[t] += add; __syncthreads();
        }
        p.blko[l * NBLK + b] = s[t] - v;
        if (b == NBLK - 1) tot[32 + l] = s[t];
        __syncthreads();
    }
    if (t == 0) { int a = 0; for (int l = 0; l < NLVL; l++) { meta[96 + l] = a; a += tot[l]; } meta[96 + NLVL] = a; }
    if (t == 1) { int a = 0; for (int l = 0; l < NLVL; l++) { meta[128 + l] = a; a += tot[16 + l]; } meta[128 + NLVL] = a; }
    if (t == 2) { int a = 0; for (int l = 0; l < NB; l++) { meta[160 + l] = a; a += tot[32 + l]; } meta[160 + NB] = a; }
    __syncthreads();
    for (int i = t; i < NLVL * NBLK; i += 1024) p.blkf[i] += meta[96 + (i >> 8)];
    for (int i = t; i < NLVL * NBLK; i += 1024) p.blkb[i] += meta[128 + (i >> 8)];
    for (int i = t; i < NB * NBLK; i += 1024) p.blko[i] += meta[160 + (i >> 8)];
    // bsums scan (rowptr block offsets)
    int v = (t < nblk) ? bsums[t] : 0;
    s[t] = v;
    __syncthreads();
    for (int off = 1; off < 1024; off <<= 1) {
        int add = (t >= off) ? s[t - off] : 0;
        __syncthreads();
        s[t] += add;
        __syncthreads();
    }
    if (t < nblk) bsums[t] = s[t] - v;
}

__global__ void k_scan_add(int* __restrict__ rowptr, int* __restrict__ cursor, int M, int total,
                           const int* __restrict__ bsums) {
    int g = blockIdx.x * blockDim.x + threadIdx.x;
    if (g >= M) return;
    int r = rowptr[g] + bsums[g >> 9];
    rowptr[g] = r;
    cursor[g] = r;
    if (g == 0) rowptr[M] = total;
}

// ---------------- edge scatter into CSR (high-occupancy grid-stride) --------
__global__ void k_edge_fill(Params p) {
    int g = blockIdx.x * 256 + threadIdx.x, gs = gridDim.x * 256;
    int N = p.N;
    for (int e = g; e < p.E; e += gs) {
        int s = p.src[e], d = p.dst[e];
        p.col[atomicAdd(&p.cursor[d], 1)] = s | (p.plarr[s] << 18);      // in-edge: other = src
        p.col[atomicAdd(&p.cursor[N + s], 1)] = d | (p.plarr[d] << 18);  // out-edge: other = dst
    }
}

// ---------------- node scatter from precomputed per-block bases --------------
__global__ void k_fill(Params p) {
    __shared__ int cur[48];     // fwd [0..12), bwd [16..28), out [32..48)
    int tid = threadIdx.x, bid = blockIdx.x;
    int N = p.N;
    if (tid < NLVL) { cur[tid] = p.blkf[tid * NBLK + bid]; cur[16 + tid] = p.blkb[tid * NBLK + bid]; }
    if (tid < NB) cur[32 + tid] = p.blko[tid * NBLK + bid];
    __syncthreads();
    int chunk = (N + gridDim.x - 1) / gridDim.x;
    int lo = bid * chunk, hi = lo + chunk; if (hi > N) hi = N;
    for (int i = lo + tid; i < hi; i += 256) {
        int pl = p.plarr[i];
        int lf = pl & 15, lb = (pl >> 4) & 15, tx = (pl >> 8) & 15;
        int pk = i | (pl << 18);
        p.nb_f[atomicAdd(&cur[lf], 1)] = pk;
        p.nb_b[atomicAdd(&cur[16 + lb], 1)] = pk;
        if (tx >= 3 && tx < 6)                          // nt == 1
            p.onodes[atomicAdd(&cur[32 + p.batch[i]], 1)] = pk;
    }
}

// ---------------- per-level sweep body (quarter-per-node gather + VALU matvec)
// (zero DS ops; broadcast via v_readlane — champion code; h-store is an
// agent-scope relaxed atomic store = write-through to the coherence point)
template <int DIR>
__device__ __forceinline__ void sweep_level(const Params& p, int lvl,
                                            const float (&w)[64], float bv,
                                            int lane, int wid, int nw, int q, int fb) {
    const int* nb = DIR ? p.nb_b : p.nb_f;
    const int* rp = p.rowptr + (DIR ? p.N : 0);
    int start = p.meta[(DIR ? 128 : 96) + lvl];
    int cnt   = p.meta[(DIR ? 128 : 96) + lvl + 1] - start;
    float* db = DIR ? p.hB : p.hN;

    int c0 = (int)((long long)cnt * wid / nw);
    int c1 = (int)((long long)cnt * (wid + 1) / nw);
    for (int i = c0; i < c1; i += 4) {
        int my = i + q;
        int v = 0, rpv = 0, rpe = 0;
        if (my < c1) {
            int e = nb[start + my];
            v = e & 0x3FFFF;
            rpv = rp[v]; rpe = rp[v + 1];
        }
        float4 acc = make_float4(0.f, 0.f, 0.f, 0.f);
        for (int cb = rpv; cb < rpe; cb++) {
            int cu = p.col[cb];
            int u = cu & 0x3FFFF;
            int flu = (cu >> 18) & 15, blu = (cu >> 22) & 15;
            const float* sp;
            if (DIR == 0)
                sp = (flu > 0 && flu < lvl) ? (p.hN + (size_t)u * 64)
                                            : (p.tabg + ((cu >> 26) & 15) * 64);
            else
                sp = (blu > 0 && blu < lvl) ? (p.hB + (size_t)u * 64)
                   : (flu > 0)              ? (p.hN + (size_t)u * 64)
                                            : (p.tabg + ((cu >> 26) & 15) * 64);
            const float4 x = *(const float4*)(sp + fb);
            acc.x += x.x; acc.y += x.y; acc.z += x.z; acc.w += x.w;
        }
        #pragma unroll
        for (int qq = 0; qq < 4; qq++) {
            if (i + qq >= c1) break;                    // wave-uniform
            int vs   = __builtin_amdgcn_readlane(v, 16 * qq);
            int degs = __builtin_amdgcn_readlane(rpe, 16 * qq)
                     - __builtin_amdgcn_readlane(rpv, 16 * qq);
            float o = bv * (float)degs;
            #pragma unroll
            for (int m = 0; m < 16; m++) {
                float ax = rlanef(acc.x, 16 * qq + m);
                float ay = rlanef(acc.y, 16 * qq + m);
                float az = rlanef(acc.z, 16 * qq + m);
                float aw = rlanef(acc.w, 16 * qq + m);
                o = fmaf(ax, w[4 * m + 0], o);
                o = fmaf(ay, w[4 * m + 1], o);
                o = fmaf(az, w[4 * m + 2], o);
                o = fmaf(aw, w[4 * m + 3], o);
            }
            // write-through to coherence point: agent-visible once vmcnt drains
            // (at the next __syncthreads), so the barrier needs no wbl2/inv
            __hip_atomic_store(&db[(size_t)vs * 64 + lane], o,
                               __ATOMIC_RELAXED, __HIP_MEMORY_SCOPE_AGENT);
        }
    }
}

// ---------------- fused sweep: all 22 levels, W loaded once per direction ----
// waves_per_eu(4,4): full 128-reg budget (w[64] lives in AGPRs, unified file).
__global__ __launch_bounds__(256) __attribute__((amdgpu_waves_per_eu(4, 4)))
void k_sweep_all(Params p) {
    const int tid = threadIdx.x, lane = tid & 63;
    const int wid = (blockIdx.x * 256 + tid) >> 6;
    const int nw  = (gridDim.x * 256) >> 6;
    const int q = lane >> 4, fb = (lane & 15) * 4;
    int* bar = p.bar;
    const int nblk = gridDim.x;
    int t = 0;

    {   // forward pass
        float w[64];
        #pragma unroll
        for (int k = 0; k < 64; k++) w[k] = p.Wf[k * 64 + lane];
        float bv = p.bf[lane];
        for (int lvl = 1; lvl < NLVL; lvl++) {
            sweep_level<0>(p, lvl, w, bv, lane, wid, nw, q, fb);
            gbar3(bar, nblk, ++t);                      // also fences fwd->bwd
        }
    }
    {   // backward pass
        float w[64];
        #pragma unroll
        for (int k = 0; k < 64; k++) w[k] = p.Wb[k * 64 + lane];
        float bv = p.bb[lane];
        for (int lvl = 1; lvl < NLVL; lvl++) {
            sweep_level<1>(p, lvl, w, bv, lane, wid, nw, q, fb);
            if (lvl < NLVL - 1) gbar3(bar, nblk, ++t);  // none after last level
        }
    }
}

// ---------------- fallback per-level sweep (identical body) ------------------
__global__ __launch_bounds__(256) __attribute__((amdgpu_waves_per_eu(4, 4)))
void k_sweep(Params p, int lvl, int dir) {
    const int tid = threadIdx.x, lane = tid & 63;
    const float* W = dir ? p.Wb : p.Wf;
    float w[64];
    #pragma unroll
    for (int k = 0; k < 64; k++) w[k] = W[k * 64 + lane];
    float bv = (dir ? p.bb : p.bf)[lane];
    const int wid = (blockIdx.x * 256 + tid) >> 6;
    const int nw  = (gridDim.x * 256) >> 6;
    const int q = lane >> 4, fb = (lane & 15) * 4;
    if (dir == 0) sweep_level<0>(p, lvl, w, bv, lane, wid, nw, q, fb);
    else          sweep_level<1>(p, lvl, w, bv, lane, wid, nw, q, fb);
}

// ---------------- readout ----------------
__device__ inline void atomicMaxF(float* addr, float val) {
    int* ai = (int*)addr;
    int old = *ai;
    while (__int_as_float(old) < val) {
        int assumed = old;
        old = atomicCAS(ai, assumed, __float_as_int(val));
        if (old == assumed) break;
    }
}

__global__ void k_readout(Params p) {
    int lane = threadIdx.x & 63;
    int b = blockIdx.x >> 5;
    int sl = blockIdx.x & 31;
    int a0 = p.meta[160 + b], a1 = p.meta[161 + b];
    int cnt = a1 - a0;
    if (cnt == 0) return;
    int lo = a0 + (int)((long long)cnt * sl / 32);
    int hi = a0 + (int)((long long)cnt * (sl + 1) / 32);
    int wcnt = hi - lo;
    int wave = threadIdx.x >> 6;
    int wl = lo + (wcnt * wave) / 4;
    int wh = lo + (wcnt * (wave + 1)) / 4;
    if (wh <= wl) return;
    float mx = -FLT_MAX, sm = 0.f;
    for (int k = wl; k < wh; k += 64) {
        int take = wh - k; if (take > 64) take = 64;
        int el = (lane < take) ? p.onodes[k + lane] : 0;
        for (int j = 0; j < take; j++) {
            int e = __shfl(el, j, 64);
            int v = e & 0x3FFFF;
            int flv = (e >> 18) & 15, blv = (e >> 22) & 15;
            const float* sp = (blv > 0) ? (p.hB + (size_t)v * 64)
                            : (flv > 0) ? (p.hN + (size_t)v * 64)
                                        : (p.tabg + ((e >> 26) & 15) * 64);
            float x = sp[lane];
            mx = fmaxf(mx, x);
            sm += x;
        }
    }
    atomicMaxF(&p.out[b * 128 + lane], mx);
    atomicAdd(&p.out[b * 128 + 64 + lane], sm);
}

extern "C" void kernel_launch(void* const* d_in, const int* in_sizes, int n_in,
                              void* d_out, int out_size, void* d_ws, size_t ws_size,
                              hipStream_t stream) {
    int N = in_sizes[0];
    int E = in_sizes[2] / 2;
    int M = 2 * N;

    Params p;
    p.nt    = (const int*)d_in[0];
    p.ninv  = (const int*)d_in[1];
    p.src   = (const int*)d_in[2];
    p.dst   = (const int*)d_in[2] + E;
    p.fl    = (const int*)d_in[3];
    p.bl    = (const int*)d_in[4];
    p.batch = (const int*)d_in[5];
    p.We    = (const float*)d_in[6];
    p.be    = (const float*)d_in[7];
    p.Wf    = (const float*)d_in[8];
    p.bf    = (const float*)d_in[9];
    p.Wb    = (const float*)d_in[10];
    p.bb    = (const float*)d_in[11];
    p.out   = (float*)d_out;
    p.N = N; p.E = E; p.M = M; p.outN = out_size;

    char* ws = (char*)d_ws;
    size_t off = 0;
    auto alloc = [&](size_t bytes) -> char* {
        char* q = ws + off;
        off = (off + bytes + 255) & ~(size_t)255;
        return q;
    };
    // rowptr + meta + bar adjacent -> one memset zeroes all (incl. barrier state)
    p.rowptr = (int*)  alloc((size_t)(M + 1) * sizeof(int));
    p.meta   = (int*)  alloc(256 * sizeof(int));
    p.bar    = (int*)  alloc((size_t)(18 + SWBLK) * 32 * sizeof(int));
    size_t zbytes = (size_t)((char*)(p.bar + (18 + SWBLK) * 32) - (char*)p.rowptr);
    p.hN     = (float*)alloc((size_t)N * 64 * sizeof(float));
    p.hB     = (float*)alloc((size_t)N * 64 * sizeof(float));
    p.tabg   = (float*)alloc(9 * 64 * sizeof(float));
    p.cursor = (int*)  alloc((size_t)M * sizeof(int));
    p.col    = (int*)  alloc((size_t)2 * E * sizeof(int));
    p.nb_f   = (int*)  alloc((size_t)N * sizeof(int));
    p.nb_b   = (int*)  alloc((size_t)N * sizeof(int));
    p.onodes = (int*)  alloc((size_t)N * sizeof(int));
    p.plarr  = (int*)  alloc((size_t)N * sizeof(int));
    p.bsums  = (int*)  alloc(1024 * sizeof(int));
    p.cntf   = (int*)  alloc(NLVL * NBLK * sizeof(int));
    p.cntb   = (int*)  alloc(NLVL * NBLK * sizeof(int));
    p.cnto   = (int*)  alloc(NB * NBLK * sizeof(int));
    p.blkf   = (int*)  alloc(NLVL * NBLK * sizeof(int));
    p.blkb   = (int*)  alloc(NLVL * NBLK * sizeof(int));
    p.blko   = (int*)  alloc(NB * NBLK * sizeof(int));

    int nscan = (M + 511) / 512;            // 782 <= 1024

    hipMemsetAsync(p.rowptr, 0, zbytes, stream);
    k_edge_deg<<<EBLK, 256, 0, stream>>>(p);
    k_deg_hist<<<NBLK, 256, 0, stream>>>(p);
    k_scan1<<<nscan, 512, 0, stream>>>(p.rowptr, M, p.bsums);
    k_scan_top<<<1, 1024, 0, stream>>>(p.bsums, nscan, p, p.out, out_size);
    k_scan_add<<<(M + 255) / 256, 256, 0, stream>>>(p.rowptr, p.cursor, M, 2 * E, p.bsums);
    k_edge_fill<<<EBLK, 256, 0, stream>>>(p);
    k_fill<<<NBLK, 256, 0, stream>>>(p);

    // Regular launch when occupancy math proves all blocks co-resident (avoids
    // hipLaunchCooperativeKernel's fixed dispatch overhead); else cooperative;
    // else per-level fallback. Cached once.
    static int g_swgrid = -2;               // -2 = not probed
    if (g_swgrid == -2) {
        int mb = 0;
        if (hipOccupancyMaxActiveBlocksPerMultiprocessor(&mb, k_sweep_all, 256, 0)
                == hipSuccess && mb > 0) {
            int dev = 0;
            hipGetDevice(&dev);
            hipDeviceProp_t props;
            if (hipGetDeviceProperties(&props, dev) == hipSuccess) {
                long cap = (long)mb * props.multiProcessorCount;
                long g = cap < SWBLK ? cap : SWBLK;
                g &= ~15L;                  // gbar3 requires multiple of 16
                g_swgrid = (g >= 16) ? (int)g : -1;
            } else g_swgrid = -1;
        } else g_swgrid = -1;
    }

    bool launched = false;
    if (g_swgrid >= 16) {
        k_sweep_all<<<g_swgrid, 256, 0, stream>>>(p);
        launched = true;
    } else {
        void* kargs[] = { (void*)&p };
        launched = hipLaunchCooperativeKernel((const void*)k_sweep_all, dim3(SWBLK),
                                              dim3(256), kargs, 0, stream) == hipSuccess;
    }
    if (!launched) {
        for (int l = 1; l < NLVL; l++)
            k_sweep<<<1024, 256, 0, stream>>>(p, l, 0);
        for (int l = 1; l < NLVL; l++)
            k_sweep<<<1024, 256, 0, stream>>>(p, l, 1);
    }

    k_readout<<<NB * 32, 256, 0, stream>>>(p);
}

// Round 6
// 542.916 us; speedup vs baseline: 5.2800x; 1.0314x over previous
//
#include <hip/hip_runtime.h>
#include <float.h>

#define NLVL 12
#define NB   16
#define NBLK 256    // blocks for deg_hist / node-fill (per-block count arrays sized to this)
#define EBLK 2048   // blocks for standalone edge-scatter kernels (fallback)
#define SWBLK 1024  // persistent tail grid (4 blocks/CU x 256 CU)

// meta: [96..109) base_f | [128..141) base_b | [160..177) base_o
// bar (128B lines): [0..16) arrival sub-counters | 16 master | 17 master-release |
//                   [18..18+nblk) per-block release flags (all monotone; zeroed per launch)
// packed entry: id(18b) | fl(4b)<<18 | bl(4b)<<22 | tidx(4b)<<26   (N=200k < 2^18)
// tidx = nt*3+ninv in 0..8 -> h_init row = tabg[tidx]  (h_init never materialized)

struct Params {
    const int *nt, *ninv, *src, *dst, *fl, *bl, *batch;
    const float *We, *be, *Wf, *bf, *Wb, *bb;
    float *hN, *hB, *tabg, *out;
    int *rowptr, *cursor, *col, *nb_f, *nb_b, *onodes, *bsums, *meta, *plarr, *bar;
    int *cntf, *cntb, *cnto, *blkf, *blkb, *blko;
    int N, E, M, outN;
};

__device__ __forceinline__ float rlanef(float x, int l) {
    return __int_as_float(__builtin_amdgcn_readlane(__float_as_int(x), l));
}
// agent-scope write-through store / load / fetch_add (coherence-point ops; the
// round-3/4-validated mechanism: cross-XCD visibility with NO wbl2/inv)
__device__ __forceinline__ void sti(int* a, int v) {
    __hip_atomic_store(a, v, __ATOMIC_RELAXED, __HIP_MEMORY_SCOPE_AGENT);
}
__device__ __forceinline__ void stf(float* a, float v) {
    __hip_atomic_store(a, v, __ATOMIC_RELAXED, __HIP_MEMORY_SCOPE_AGENT);
}
__device__ __forceinline__ int ald(int* a) {
    return __hip_atomic_load(a, __ATOMIC_RELAXED, __HIP_MEMORY_SCOPE_AGENT);
}
__device__ __forceinline__ int afa(int* a, int v) {
    return __hip_atomic_fetch_add(a, v, __ATOMIC_RELAXED, __HIP_MEMORY_SCOPE_AGENT);
}

// Hierarchical maintenance-free grid barrier — round-4 proven config verbatim
// (16 arrival lines -> captains -> master -> release -> per-block private flags).
// Monotone per-flag ordering is safe: a block arrives at epoch t+1 only after
// READING its flag==t, so the t-store reached MALL before any t+1-store issues.
__device__ __forceinline__ void gbar3(int* bar, int nblk, int t) {
    __syncthreads();                       // vmcnt(0): sti/stf drained to MALL
    if (threadIdx.x == 0) {
        const int line = blockIdx.x & 15;
        const int per  = nblk >> 4;        // blocks per line (nblk multiple of 16)
        int a = afa(&bar[line * 32], 1);
        if (a == per * t - 1) {            // captain: last arrival on this line
            int m = afa(&bar[16 * 32], 1);
            if (m == 16 * t - 1) {
                sti(&bar[17 * 32], t);
            } else {
                while (ald(&bar[17 * 32]) < t) __builtin_amdgcn_s_sleep(1);
            }
            for (int b = line; b < nblk; b += 16)   // fan-out to my blocks
                sti(&bar[(18 + b) * 32], t);
        } else {
            while (ald(&bar[(18 + blockIdx.x) * 32]) < t) __builtin_amdgcn_s_sleep(4);
        }
    }
    asm volatile("" ::: "memory");         // no load motion across the wait
    __syncthreads();
}

// ---------------- edge-degree atomics (high-occupancy grid-stride) ----------
__global__ void k_edge_deg(Params p) {
    int g = blockIdx.x * 256 + threadIdx.x, gs = gridDim.x * 256;
    for (int e = g; e < p.E; e += gs) {
        atomicAdd(&p.rowptr[p.dst[e]], 1);
        atomicAdd(&p.rowptr[p.N + p.src[e]], 1);
    }
}

// ---------------- node histograms + packed (fl,bl,tidx) ----------------------
__global__ void k_deg_hist(Params p) {
    __shared__ int hf[NLVL], hb[NLVL], ho[NB];
    int tid = threadIdx.x, bid = blockIdx.x;
    if (tid < NLVL) { hf[tid] = 0; hb[tid] = 0; }
    if (tid < NB) ho[tid] = 0;
    __syncthreads();
    // chunk-owned nodes (same chunk map as the node-fill phase!)
    int chunk = (p.N + gridDim.x - 1) / gridDim.x;
    int lo = bid * chunk, hi = lo + chunk; if (hi > p.N) hi = p.N;
    for (int i = lo + tid; i < hi; i += 256) {
        int f = p.fl[i], b = p.bl[i];
        int t = p.nt[i], iv = p.ninv[i];
        p.plarr[i] = f | (b << 4) | ((t * 3 + iv) << 8);
        atomicAdd(&hf[f], 1);
        atomicAdd(&hb[b], 1);
        if (t == 1) atomicAdd(&ho[p.batch[i]], 1);
    }
    __syncthreads();
    if (tid < NLVL) { p.cntf[tid * NBLK + bid] = hf[tid]; p.cntb[tid * NBLK + bid] = hb[tid]; }
    if (tid < NB) p.cnto[tid * NBLK + bid] = ho[tid];
}

// ---------------- 3-kernel exclusive scan over M = 2N ----------------
__global__ void k_scan1(int* __restrict__ data, int M, int* __restrict__ bsums) {
    __shared__ int s[512];
    int t = threadIdx.x;
    int g = blockIdx.x * 512 + t;
    int v = (g < M) ? data[g] : 0;
    s[t] = v;
    __syncthreads();
    for (int off = 1; off < 512; off <<= 1) {
        int add = (t >= off) ? s[t - off] : 0;
        __syncthreads();
        s[t] += add;
        __syncthreads();
    }
    if (g < M) data[g] = s[t] - v;
    if (t == 511) bsums[blockIdx.x] = s[511];
}

// scan_top: bsums scan + per-block-base segmented scans + meta bases + tabg + out init
__global__ void k_scan_top(int* __restrict__ bsums, int nblk, Params p,
                           float* __restrict__ out, int outN) {
    __shared__ int s[1024];
    __shared__ int tot[48];     // fwd [0..12), bwd [16..28), out [32..48)
    int t = threadIdx.x;
    int* meta = p.meta;
    for (int i = t; i < outN; i += 1024)
        out[i] = ((i & 127) < 64) ? -FLT_MAX : 0.0f;   // max-pool init == finfo.min
    if (t < 576) {              // 9-row h_init table
        int row = t >> 6, j = t & 63;
        float nf = (float)(row / 3), iv = (float)(row % 3);
        p.tabg[t] = fmaf(nf, p.We[j], fmaf(iv, p.We[64 + j], p.be[j]));
    }
    // segmented scans: 4 segments of NBLK=256 per round
    int seg = t >> 8, b = t & 255;
    for (int r = 0; r < 3; r++) {                      // fwd levels 4r+seg
        int l = 4 * r + seg;
        int v = p.cntf[l * NBLK + b];
        s[t] = v; __syncthreads();
        for (int off = 1; off < NBLK; off <<= 1) {
            int add = (b >= off) ? s[t - off] : 0; __syncthreads();
            s[t] += add; __syncthreads();
        }
        p.blkf[l * NBLK + b] = s[t] - v;
        if (b == NBLK - 1) tot[l] = s[t];
        __syncthreads();
    }
    for (int r = 0; r < 3; r++) {                      // bwd levels
        int l = 4 * r + seg;
        int v = p.cntb[l * NBLK + b];
        s[t] = v; __syncthreads();
        for (int off = 1; off < NBLK; off <<= 1) {
            int add = (b >= off) ? s[t - off] : 0; __syncthreads();
            s[t] += add; __syncthreads();
        }
        p.blkb[l * NBLK + b] = s[t] - v;
        if (b == NBLK - 1) tot[16 + l] = s[t];
        __syncthreads();
    }
    for (int r = 0; r < 4; r++) {                      // output-node batches
        int l = 4 * r + seg;
        int v = p.cnto[l * NBLK + b];
        s[t] = v; __syncthreads();
        for (int off = 1; off < NBLK; off <<= 1) {
            int add = (b >= off) ? s[t - off] : 0; __syncthreads();
            s[t] += add; __syncthreads();
        }
        p.blko[l * NBLK + b] = s[t] - v;
        if (b == NBLK - 1) tot[32 + l] = s[t];
        __syncthreads();
    }
    if (t == 0) { int a = 0; for (int l = 0; l < NLVL; l++) { meta[96 + l] = a; a += tot[l]; } meta[96 + NLVL] = a; }
    if (t == 1) { int a = 0; for (int l = 0; l < NLVL; l++) { meta[128 + l] = a; a += tot[16 + l]; } meta[128 + NLVL] = a; }
    if (t == 2) { int a = 0; for (int l = 0; l < NB; l++) { meta[160 + l] = a; a += tot[32 + l]; } meta[160 + NB] = a; }
    __syncthreads();
    for (int i = t; i < NLVL * NBLK; i += 1024) p.blkf[i] += meta[96 + (i >> 8)];
    for (int i = t; i < NLVL * NBLK; i += 1024) p.blkb[i] += meta[128 + (i >> 8)];
    for (int i = t; i < NB * NBLK; i += 1024) p.blko[i] += meta[160 + (i >> 8)];
    // bsums scan (rowptr block offsets)
    int v = (t < nblk) ? bsums[t] : 0;
    s[t] = v;
    __syncthreads();
    for (int off = 1; off < 1024; off <<= 1) {
        int add = (t >= off) ? s[t - off] : 0;
        __syncthreads();
        s[t] += add;
        __syncthreads();
    }
    if (t < nblk) bsums[t] = s[t] - v;
}

__global__ void k_scan_add(int* __restrict__ rowptr, int* __restrict__ cursor, int M, int total,
                           const int* __restrict__ bsums) {
    int g = blockIdx.x * blockDim.x + threadIdx.x;
    if (g >= M) return;
    int r = rowptr[g] + bsums[g >> 9];
    rowptr[g] = r;
    cursor[g] = r;
    if (g == 0) rowptr[M] = total;
}

// ---------------- per-level sweep body (champion code, unchanged arithmetic) ----
template <int DIR>
__device__ __forceinline__ void sweep_level(const Params& p, int lvl,
                                            const float (&w)[64], float bv,
                                            int lane, int wid, int nw, int q, int fb) {
    const int* nb = DIR ? p.nb_b : p.nb_f;
    const int* rp = p.rowptr + (DIR ? p.N : 0);
    int start = p.meta[(DIR ? 128 : 96) + lvl];
    int cnt   = p.meta[(DIR ? 128 : 96) + lvl + 1] - start;
    float* db = DIR ? p.hB : p.hN;

    int c0 = (int)((long long)cnt * wid / nw);
    int c1 = (int)((long long)cnt * (wid + 1) / nw);
    for (int i = c0; i < c1; i += 4) {
        int my = i + q;
        int v = 0, rpv = 0, rpe = 0;
        if (my < c1) {
            int e = nb[start + my];
            v = e & 0x3FFFF;
            rpv = rp[v]; rpe = rp[v + 1];
        }
        float4 acc = make_float4(0.f, 0.f, 0.f, 0.f);
        for (int cb = rpv; cb < rpe; cb++) {
            int cu = p.col[cb];
            int u = cu & 0x3FFFF;
            int flu = (cu >> 18) & 15, blu = (cu >> 22) & 15;
            const float* sp;
            if (DIR == 0)
                sp = (flu > 0 && flu < lvl) ? (p.hN + (size_t)u * 64)
                                            : (p.tabg + ((cu >> 26) & 15) * 64);
            else
                sp = (blu > 0 && blu < lvl) ? (p.hB + (size_t)u * 64)
                   : (flu > 0)              ? (p.hN + (size_t)u * 64)
                                            : (p.tabg + ((cu >> 26) & 15) * 64);
            const float4 x = *(const float4*)(sp + fb);
            acc.x += x.x; acc.y += x.y; acc.z += x.z; acc.w += x.w;
        }
        #pragma unroll
        for (int qq = 0; qq < 4; qq++) {
            if (i + qq >= c1) break;                    // wave-uniform
            int vs   = __builtin_amdgcn_readlane(v, 16 * qq);
            int degs = __builtin_amdgcn_readlane(rpe, 16 * qq)
                     - __builtin_amdgcn_readlane(rpv, 16 * qq);
            float o = bv * (float)degs;
            #pragma unroll
            for (int m = 0; m < 16; m++) {
                float ax = rlanef(acc.x, 16 * qq + m);
                float ay = rlanef(acc.y, 16 * qq + m);
                float az = rlanef(acc.z, 16 * qq + m);
                float aw = rlanef(acc.w, 16 * qq + m);
                o = fmaf(ax, w[4 * m + 0], o);
                o = fmaf(ay, w[4 * m + 1], o);
                o = fmaf(az, w[4 * m + 2], o);
                o = fmaf(aw, w[4 * m + 3], o);
            }
            stf(&db[(size_t)vs * 64 + lane], o);        // write-through, agent-visible
        }
    }
}

// ---------------- readout body (shared by fused tail and fallback kernel) ----
__device__ inline void atomicMaxF(float* addr, float val) {
    int* ai = (int*)addr;
    int old = *ai;
    while (__int_as_float(old) < val) {
        int assumed = old;
        old = atomicCAS(ai, assumed, __float_as_int(val));
        if (old == assumed) break;
    }
}

__device__ __forceinline__ void readout_body(const Params& p, int bid, int tid) {
    int lane = tid & 63;
    int b = bid >> 5;
    int sl = bid & 31;
    int a0 = p.meta[160 + b], a1 = p.meta[161 + b];
    int cnt = a1 - a0;
    if (cnt == 0) return;
    int lo = a0 + (int)((long long)cnt * sl / 32);
    int hi = a0 + (int)((long long)cnt * (sl + 1) / 32);
    int wcnt = hi - lo;
    int wave = tid >> 6;
    int wl = lo + (wcnt * wave) / 4;
    int wh = lo + (wcnt * (wave + 1)) / 4;
    if (wh <= wl) return;
    float mx = -FLT_MAX, sm = 0.f;
    for (int k = wl; k < wh; k += 64) {
        int take = wh - k; if (take > 64) take = 64;
        int el = (lane < take) ? p.onodes[k + lane] : 0;
        for (int j = 0; j < take; j++) {
            int e = __shfl(el, j, 64);
            int v = e & 0x3FFFF;
            int flv = (e >> 18) & 15, blv = (e >> 22) & 15;
            const float* sp = (blv > 0) ? (p.hB + (size_t)v * 64)
                            : (flv > 0) ? (p.hN + (size_t)v * 64)
                                        : (p.tabg + ((e >> 26) & 15) * 64);
            float x = sp[lane];
            mx = fmaxf(mx, x);
            sm += x;
        }
    }
    atomicMaxF(&p.out[b * 128 + lane], mx);
    atomicAdd(&p.out[b * 128 + 64 + lane], sm);
}

// ===== persistent TAIL kernel: edge fill + node fill + 22 sweeps + readout ====
// All prep data (rowptr/cursor/blk*/meta/plarr/tabg/out-init) comes from the
// separate proven kernels across a real kernel boundary. Everything produced
// INSIDE this kernel that crosses an internal barrier (col, nb_*, onodes, hN,
// hB) uses the validated agent-scope write-through stores.
__global__ __launch_bounds__(256) __attribute__((amdgpu_waves_per_eu(4, 4)))
void k_tail(Params p) {
    const int tid = threadIdx.x, bid = blockIdx.x;
    const int lane = tid & 63;
    int* bar = p.bar;
    const int nblk = gridDim.x;            // multiple of 16, >= NBLK
    int ep = 0;
    __shared__ int cur[48];

    // ---- PF1a: edge scatter into CSR (all blocks, grid-stride) --------------
    for (int e = bid * 256 + tid; e < p.E; e += nblk * 256) {
        int sN = p.src[e], d = p.dst[e];
        sti(&p.col[atomicAdd(&p.cursor[d], 1)],        sN | (p.plarr[sN] << 18));
        sti(&p.col[atomicAdd(&p.cursor[p.N + sN], 1)],  d | (p.plarr[d]  << 18));
    }
    // ---- PF1b: node bucket scatter (blocks 0..NBLK-1, round-4 k_fill logic) -
    if (bid < NBLK) {
        if (tid < NLVL) { cur[tid] = p.blkf[tid * NBLK + bid]; cur[16 + tid] = p.blkb[tid * NBLK + bid]; }
        if (tid < NB) cur[32 + tid] = p.blko[tid * NBLK + bid];
        __syncthreads();
        int chunk = (p.N + NBLK - 1) / NBLK;
        int lo = bid * chunk, hi = lo + chunk; if (hi > p.N) hi = p.N;
        for (int i = lo + tid; i < hi; i += 256) {
            int pl = p.plarr[i];
            int lf = pl & 15, lb = (pl >> 4) & 15, tx = (pl >> 8) & 15;
            int pk = i | (pl << 18);
            sti(&p.nb_f[atomicAdd(&cur[lf], 1)], pk);
            sti(&p.nb_b[atomicAdd(&cur[16 + lb], 1)], pk);
            if (tx >= 3 && tx < 6)                      // nt == 1
                sti(&p.onodes[atomicAdd(&cur[32 + p.batch[i]], 1)], pk);
        }
    }
    gbar3(bar, nblk, ++ep);

    // ---- 22 sweep levels, W loaded once per direction ------------------------
    const int wid = (bid * 256 + tid) >> 6;
    const int nw  = (nblk * 256) >> 6;
    const int q = lane >> 4, fb = (lane & 15) * 4;
    {
        float w[64];
        #pragma unroll
        for (int k = 0; k < 64; k++) w[k] = p.Wf[k * 64 + lane];
        float bv = p.bf[lane];
        for (int lvl = 1; lvl < NLVL; lvl++) {
            sweep_level<0>(p, lvl, w, bv, lane, wid, nw, q, fb);
            gbar3(bar, nblk, ++ep);
        }
    }
    {
        float w[64];
        #pragma unroll
        for (int k = 0; k < 64; k++) w[k] = p.Wb[k * 64 + lane];
        float bv = p.bb[lane];
        for (int lvl = 1; lvl < NLVL; lvl++) {
            sweep_level<1>(p, lvl, w, bv, lane, wid, nw, q, fb);
            gbar3(bar, nblk, ++ep);                     // incl. bar before readout
        }
    }

    // ---- readout -------------------------------------------------------------
    if (bid < NB * 32) readout_body(p, bid, tid);
}

// ================= fallback kernels (round-0/round-4 proven path) =============
__global__ void k_edge_fill(Params p) {
    int g = blockIdx.x * 256 + threadIdx.x, gs = gridDim.x * 256;
    int N = p.N;
    for (int e = g; e < p.E; e += gs) {
        int s = p.src[e], d = p.dst[e];
        p.col[atomicAdd(&p.cursor[d], 1)] = s | (p.plarr[s] << 18);
        p.col[atomicAdd(&p.cursor[N + s], 1)] = d | (p.plarr[d] << 18);
    }
}

__global__ void k_fill(Params p) {
    __shared__ int cur[48];
    int tid = threadIdx.x, bid = blockIdx.x;
    int N = p.N;
    if (tid < NLVL) { cur[tid] = p.blkf[tid * NBLK + bid]; cur[16 + tid] = p.blkb[tid * NBLK + bid]; }
    if (tid < NB) cur[32 + tid] = p.blko[tid * NBLK + bid];
    __syncthreads();
    int chunk = (N + gridDim.x - 1) / gridDim.x;
    int lo = bid * chunk, hi = lo + chunk; if (hi > N) hi = N;
    for (int i = lo + tid; i < hi; i += 256) {
        int pl = p.plarr[i];
        int lf = pl & 15, lb = (pl >> 4) & 15, tx = (pl >> 8) & 15;
        int pk = i | (pl << 18);
        p.nb_f[atomicAdd(&cur[lf], 1)] = pk;
        p.nb_b[atomicAdd(&cur[16 + lb], 1)] = pk;
        if (tx >= 3 && tx < 6)
            p.onodes[atomicAdd(&cur[32 + p.batch[i]], 1)] = pk;
    }
}

__global__ __launch_bounds__(256) __attribute__((amdgpu_waves_per_eu(4, 4)))
void k_sweep(Params p, int lvl, int dir) {
    const int tid = threadIdx.x, lane = tid & 63;
    const float* W = dir ? p.Wb : p.Wf;
    float w[64];
    #pragma unroll
    for (int k = 0; k < 64; k++) w[k] = W[k * 64 + lane];
    float bv = (dir ? p.bb : p.bf)[lane];
    const int wid = (blockIdx.x * 256 + tid) >> 6;
    const int nw  = (gridDim.x * 256) >> 6;
    const int q = lane >> 4, fb = (lane & 15) * 4;
    if (dir == 0) sweep_level<0>(p, lvl, w, bv, lane, wid, nw, q, fb);
    else          sweep_level<1>(p, lvl, w, bv, lane, wid, nw, q, fb);
}

__global__ void k_readout(Params p) {
    readout_body(p, blockIdx.x, threadIdx.x);
}

extern "C" void kernel_launch(void* const* d_in, const int* in_sizes, int n_in,
                              void* d_out, int out_size, void* d_ws, size_t ws_size,
                              hipStream_t stream) {
    int N = in_sizes[0];
    int E = in_sizes[2] / 2;
    int M = 2 * N;

    Params p;
    p.nt    = (const int*)d_in[0];
    p.ninv  = (const int*)d_in[1];
    p.src   = (const int*)d_in[2];
    p.dst   = (const int*)d_in[2] + E;
    p.fl    = (const int*)d_in[3];
    p.bl    = (const int*)d_in[4];
    p.batch = (const int*)d_in[5];
    p.We    = (const float*)d_in[6];
    p.be    = (const float*)d_in[7];
    p.Wf    = (const float*)d_in[8];
    p.bf    = (const float*)d_in[9];
    p.Wb    = (const float*)d_in[10];
    p.bb    = (const float*)d_in[11];
    p.out   = (float*)d_out;
    p.N = N; p.E = E; p.M = M; p.outN = out_size;

    char* ws = (char*)d_ws;
    size_t off = 0;
    auto alloc = [&](size_t bytes) -> char* {
        char* q = ws + off;
        off = (off + bytes + 255) & ~(size_t)255;
        return q;
    };
    // rowptr + meta + bar adjacent -> one memset zeroes all (round-4 footprint)
    p.rowptr = (int*)  alloc((size_t)(M + 1) * sizeof(int));
    p.meta   = (int*)  alloc(256 * sizeof(int));
    p.bar    = (int*)  alloc((size_t)(18 + SWBLK) * 32 * sizeof(int));
    size_t zbytes = (size_t)((char*)(p.bar + (18 + SWBLK) * 32) - (char*)p.rowptr);
    p.hN     = (float*)alloc((size_t)N * 64 * sizeof(float));
    p.hB     = (float*)alloc((size_t)N * 64 * sizeof(float));
    p.tabg   = (float*)alloc(9 * 64 * sizeof(float));
    p.cursor = (int*)  alloc((size_t)M * sizeof(int));
    p.col    = (int*)  alloc((size_t)2 * E * sizeof(int));
    p.nb_f   = (int*)  alloc((size_t)N * sizeof(int));
    p.nb_b   = (int*)  alloc((size_t)N * sizeof(int));
    p.onodes = (int*)  alloc((size_t)N * sizeof(int));
    p.plarr  = (int*)  alloc((size_t)N * sizeof(int));
    p.bsums  = (int*)  alloc(1024 * sizeof(int));
    p.cntf   = (int*)  alloc(NLVL * NBLK * sizeof(int));
    p.cntb   = (int*)  alloc(NLVL * NBLK * sizeof(int));
    p.cnto   = (int*)  alloc(NB * NBLK * sizeof(int));
    p.blkf   = (int*)  alloc(NLVL * NBLK * sizeof(int));
    p.blkb   = (int*)  alloc(NLVL * NBLK * sizeof(int));
    p.blko   = (int*)  alloc(NB * NBLK * sizeof(int));

    int nscan = (M + 511) / 512;            // 782 <= 1024

    // tail path requires co-residency at the launched grid (round-4 proven probe)
    static int g_tail = -2;                 // -2 = not probed
    if (g_tail == -2) {
        int mb = 0;
        g_tail = -1;
        if (hipOccupancyMaxActiveBlocksPerMultiprocessor(&mb, k_tail, 256, 0) == hipSuccess
                && mb > 0) {
            int dev = 0;
            hipGetDevice(&dev);
            hipDeviceProp_t props;
            if (hipGetDeviceProperties(&props, dev) == hipSuccess) {
                long cap = (long)mb * props.multiProcessorCount;
                long g = cap < SWBLK ? cap : SWBLK;
                g &= ~15L;                  // gbar3 requires multiple of 16
                if (g >= NBLK) g_tail = (int)g;   // node-fill needs >= NBLK blocks
            }
        }
    }

    hipMemsetAsync(p.rowptr, 0, zbytes, stream);
    k_edge_deg<<<EBLK, 256, 0, stream>>>(p);
    k_deg_hist<<<NBLK, 256, 0, stream>>>(p);
    k_scan1<<<nscan, 512, 0, stream>>>(p.rowptr, M, p.bsums);
    k_scan_top<<<1, 1024, 0, stream>>>(p.bsums, nscan, p, p.out, out_size);
    k_scan_add<<<(M + 255) / 256, 256, 0, stream>>>(p.rowptr, p.cursor, M, 2 * E, p.bsums);

    bool launched = false;
    if (g_tail >= NBLK) {
        k_tail<<<g_tail, 256, 0, stream>>>(p);
        launched = true;
    } else {
        void* kargs[] = { (void*)&p };
        launched = hipLaunchCooperativeKernel((const void*)k_tail, dim3(SWBLK),
                                              dim3(256), kargs, 0, stream) == hipSuccess;
    }
    if (!launched) {
        // fallback: proven multi-kernel path
        k_edge_fill<<<EBLK, 256, 0, stream>>>(p);
        k_fill<<<NBLK, 256, 0, stream>>>(p);
        for (int l = 1; l < NLVL; l++)
            k_sweep<<<1024, 256, 0, stream>>>(p, l, 0);
        for (int l = 1; l < NLVL; l++)
            k_sweep<<<1024, 256, 0, stream>>>(p, l, 1);
        k_readout<<<NB * 32, 256, 0, stream>>>(p);
    }
}

// Round 7
// 496.664 us; speedup vs baseline: 5.7717x; 1.0931x over previous
//
#include <hip/hip_runtime.h>
#include <float.h>

#define NLVL 12
#define NB   16
#define NBLK 256    // node-hist / node-fill block count (cnt/blk arrays are NBLK-wide)
#define EBLK 2048   // fallback edge-scatter grid
#define FG   1024   // fused persistent grid (4 blocks/CU x 256 CU)

// meta: [96..109) base_f | [128..141) base_b | [160..177) base_o | [224..264) seg totals
// bar (128B lines): [0..16) arrival | 16 master | 17 release | [18..18+FG) per-block flags
// packed entry: id(18b) | fl(4b)<<18 | bl(4b)<<22 | tidx(4b)<<26   (N=200k < 2^18)
//
// COHERENCE DISCIPLINE (validated r3-r6): producer stores crossing an internal
// barrier are agent-scope write-through (sti/stf); consumers may use PLAIN loads
// iff the line's final write precedes its first fetch by any cache ("write-once").
// Round-5's hang: in-place RMW (rowptr/blk) broke write-once -> stale L1/L2 reads.
// Fix here: deg -> rowscan -> rowptr and blkS -> blkF are SEPARATE write-once arrays.

struct Params {
    const int *nt, *ninv, *src, *dst, *fl, *bl, *batch;
    const float *We, *be, *Wf, *bf, *Wb, *bb;
    float *hN, *hB, *tabg, *out;
    int *rowptr, *cursor, *col, *nb_f, *nb_b, *onodes, *bsums, *bsums2, *meta, *plarr, *bar;
    int *deg, *rowscan;
    int *cntf, *cntb, *cnto, *blkf, *blkb, *blko;      // blk* = P2 seg-scan output (blkS)
    int *blkFf, *blkFb, *blkFo;                        // P4 final bases (write-once)
    int N, E, M, outN;
};

__device__ __forceinline__ float rlanef(float x, int l) {
    return __int_as_float(__builtin_amdgcn_readlane(__float_as_int(x), l));
}
__device__ __forceinline__ void sti(int* a, int v) {
    __hip_atomic_store(a, v, __ATOMIC_RELAXED, __HIP_MEMORY_SCOPE_AGENT);
}
__device__ __forceinline__ void stf(float* a, float v) {
    __hip_atomic_store(a, v, __ATOMIC_RELAXED, __HIP_MEMORY_SCOPE_AGENT);
}
__device__ __forceinline__ int ald(int* a) {
    return __hip_atomic_load(a, __ATOMIC_RELAXED, __HIP_MEMORY_SCOPE_AGENT);
}
__device__ __forceinline__ int afa(int* a, int v) {
    return __hip_atomic_fetch_add(a, v, __ATOMIC_RELAXED, __HIP_MEMORY_SCOPE_AGENT);
}

// Hierarchical maintenance-free grid barrier — round-4/6 proven verbatim.
__device__ __forceinline__ void gbar3(int* bar, int nblk, int t) {
    __syncthreads();                       // vmcnt(0): sti/stf drained to MALL
    if (threadIdx.x == 0) {
        const int line = blockIdx.x & 15;
        const int per  = nblk >> 4;
        int a = afa(&bar[line * 32], 1);
        if (a == per * t - 1) {
            int m = afa(&bar[16 * 32], 1);
            if (m == 16 * t - 1) {
                sti(&bar[17 * 32], t);
            } else {
                while (ald(&bar[17 * 32]) < t) __builtin_amdgcn_s_sleep(1);
            }
            for (int b = line; b < nblk; b += 16)
                sti(&bar[(18 + b) * 32], t);
        } else {
            while (ald(&bar[(18 + blockIdx.x) * 32]) < t) __builtin_amdgcn_s_sleep(4);
        }
    }
    asm volatile("" ::: "memory");
    __syncthreads();
}

// block-local inclusive scan (256 threads, one int each)
__device__ __forceinline__ int blockScanIncl(int v, int* s, int t) {
    s[t] = v; __syncthreads();
    for (int off = 1; off < 256; off <<= 1) {
        int add = (t >= off) ? s[t - off] : 0; __syncthreads();
        s[t] += add; __syncthreads();
    }
    int r = s[t]; __syncthreads();
    return r;
}

// ---------------- per-level sweep body (champion arithmetic + no-op clamps) ----
// Clamps are hang-insurance: on valid data (deg <= ~25) they never bind; on
// corrupted CSR they bound the gather loop so failure = wrong answer, not hang.
template <int DIR>
__device__ __forceinline__ void sweep_level(const Params& p, int lvl,
                                            const float (&w)[64], float bv,
                                            int lane, int wid, int nw, int q, int fb) {
    const int* nb = DIR ? p.nb_b : p.nb_f;
    const int* rp = p.rowptr + (DIR ? p.N : 0);
    int start = p.meta[(DIR ? 128 : 96) + lvl];
    int cnt   = p.meta[(DIR ? 128 : 96) + lvl + 1] - start;
    float* db = DIR ? p.hB : p.hN;
    const int e2 = 2 * p.E;

    int c0 = (int)((long long)cnt * wid / nw);
    int c1 = (int)((long long)cnt * (wid + 1) / nw);
    for (int i = c0; i < c1; i += 4) {
        int my = i + q;
        int v = 0, rpv = 0, rpe = 0;
        if (my < c1) {
            int e = nb[start + my];
            v = e & 0x3FFFF;
            rpv = rp[v]; rpe = rp[v + 1];
            rpv = (rpv < 0) ? 0 : (rpv > e2 ? e2 : rpv);
            rpe = (rpe < rpv) ? rpv : (rpe > e2 ? e2 : rpe);
            if (rpe > rpv + 4096) rpe = rpv + 4096;
        }
        float4 acc = make_float4(0.f, 0.f, 0.f, 0.f);
        for (int cb = rpv; cb < rpe; cb++) {
            int cu = p.col[cb];
            int u = cu & 0x3FFFF;
            int flu = (cu >> 18) & 15, blu = (cu >> 22) & 15;
            const float* sp;
            if (DIR == 0)
                sp = (flu > 0 && flu < lvl) ? (p.hN + (size_t)u * 64)
                                            : (p.tabg + ((cu >> 26) & 15) * 64);
            else
                sp = (blu > 0 && blu < lvl) ? (p.hB + (size_t)u * 64)
                   : (flu > 0)              ? (p.hN + (size_t)u * 64)
                                            : (p.tabg + ((cu >> 26) & 15) * 64);
            const float4 x = *(const float4*)(sp + fb);
            acc.x += x.x; acc.y += x.y; acc.z += x.z; acc.w += x.w;
        }
        #pragma unroll
        for (int qq = 0; qq < 4; qq++) {
            if (i + qq >= c1) break;                    // wave-uniform
            int vs   = __builtin_amdgcn_readlane(v, 16 * qq);
            int degs = __builtin_amdgcn_readlane(rpe, 16 * qq)
                     - __builtin_amdgcn_readlane(rpv, 16 * qq);
            float o = bv * (float)degs;
            #pragma unroll
            for (int m = 0; m < 16; m++) {
                float ax = rlanef(acc.x, 16 * qq + m);
                float ay = rlanef(acc.y, 16 * qq + m);
                float az = rlanef(acc.z, 16 * qq + m);
                float aw = rlanef(acc.w, 16 * qq + m);
                o = fmaf(ax, w[4 * m + 0], o);
                o = fmaf(ay, w[4 * m + 1], o);
                o = fmaf(az, w[4 * m + 2], o);
                o = fmaf(aw, w[4 * m + 3], o);
            }
            stf(&db[(size_t)vs * 64 + lane], o);        // write-through, agent-visible
        }
    }
}

// ---------------- readout body (shared; clamps are no-op on valid meta) -------
__device__ inline void atomicMaxF(float* addr, float val) {
    int* ai = (int*)addr;
    int old = *ai;
    while (__int_as_float(old) < val) {
        int assumed = old;
        old = atomicCAS(ai, assumed, __float_as_int(val));
        if (old == assumed) break;
    }
}

__device__ __forceinline__ void readout_body(const Params& p, int bid, int tid) {
    int lane = tid & 63;
    int b = bid >> 5;
    int sl = bid & 31;
    int a0 = p.meta[160 + b], a1 = p.meta[161 + b];
    a0 = (a0 < 0) ? 0 : (a0 > p.N ? p.N : a0);
    a1 = (a1 < a0) ? a0 : (a1 > p.N ? p.N : a1);
    int cnt = a1 - a0;
    if (cnt == 0) return;
    int lo = a0 + (int)((long long)cnt * sl / 32);
    int hi = a0 + (int)((long long)cnt * (sl + 1) / 32);
    int wcnt = hi - lo;
    int wave = tid >> 6;
    int wl = lo + (wcnt * wave) / 4;
    int wh = lo + (wcnt * (wave + 1)) / 4;
    if (wh <= wl) return;
    float mx = -FLT_MAX, sm = 0.f;
    for (int k = wl; k < wh; k += 64) {
        int take = wh - k; if (take > 64) take = 64;
        int el = (lane < take) ? p.onodes[k + lane] : 0;
        for (int j = 0; j < take; j++) {
            int e = __shfl(el, j, 64);
            int v = e & 0x3FFFF;
            int flv = (e >> 18) & 15, blv = (e >> 22) & 15;
            const float* sp = (blv > 0) ? (p.hB + (size_t)v * 64)
                            : (flv > 0) ? (p.hN + (size_t)v * 64)
                                        : (p.tabg + ((e >> 26) & 15) * 64);
            float x = sp[lane];
            mx = fmaxf(mx, x);
            sm += x;
        }
    }
    atomicMaxF(&p.out[b * 128 + lane], mx);
    atomicAdd(&p.out[b * 128 + 64 + lane], sm);
}

// ===================== FULLY FUSED persistent kernel ==========================
__global__ __launch_bounds__(256) __attribute__((amdgpu_waves_per_eu(4, 4)))
void k_fused(Params p) {
    const int tid = threadIdx.x, bid = blockIdx.x;
    const int lane = tid & 63;
    int* bar = p.bar;
    int ep = 0;
    __shared__ int s[256];
    __shared__ int hist[40];    // fwd [0..12), bwd [12..24), out [24..40)
    __shared__ int cur[48];

    // ---- P1: edge degrees (deg, fresh array) + node hist/plarr + out/tabg ---
    if (tid < 40) hist[tid] = 0;
    __syncthreads();
    for (int e = bid * 256 + tid; e < p.E; e += FG * 256) {
        atomicAdd(&p.deg[p.dst[e]], 1);
        atomicAdd(&p.deg[p.N + p.src[e]], 1);
    }
    for (int i = bid * 256 + tid; i < p.outN; i += FG * 256)
        stf(&p.out[i], ((i & 127) < 64) ? -FLT_MAX : 0.0f);
    if (bid == 0 && tid < 64) {
        #pragma unroll
        for (int row = 0; row < 9; row++) {
            float nf = (float)(row / 3), iv = (float)(row % 3);
            stf(&p.tabg[row * 64 + tid],
                fmaf(nf, p.We[tid], fmaf(iv, p.We[64 + tid], p.be[tid])));
        }
    }
    if (bid < NBLK) {
        int chunk = (p.N + NBLK - 1) / NBLK;
        int lo = bid * chunk, hi = lo + chunk; if (hi > p.N) hi = p.N;
        for (int i = lo + tid; i < hi; i += 256) {
            int f = p.fl[i], b = p.bl[i];
            int t2 = p.nt[i], iv = p.ninv[i];
            sti(&p.plarr[i], f | (b << 4) | ((t2 * 3 + iv) << 8));
            atomicAdd(&hist[f], 1);
            atomicAdd(&hist[12 + b], 1);
            if (t2 == 1) atomicAdd(&hist[24 + p.batch[i]], 1);
        }
    }
    __syncthreads();
    if (bid < NBLK) {
        if (tid < NLVL) { sti(&p.cntf[tid * NBLK + bid], hist[tid]); sti(&p.cntb[tid * NBLK + bid], hist[12 + tid]); }
        if (tid < NB) sti(&p.cnto[tid * NBLK + bid], hist[24 + tid]);
    }
    gbar3(bar, FG, ++ep);

    // ---- P2: deg -> rowscan chunk scans (write-once) + 40 parallel seg scans -
    const int nscan = (p.M + 511) >> 9;          // 782; 782+42 <= FG
    if (bid < nscan) {
        int g0 = (bid << 9) + tid * 2;
        int e0 = (g0 < p.M) ? p.deg[g0] : 0;
        int e1 = (g0 + 1 < p.M) ? p.deg[g0 + 1] : 0;
        int incl = blockScanIncl(e0 + e1, s, tid);
        int excl = incl - (e0 + e1);
        if (g0 < p.M) sti(&p.rowscan[g0], excl);
        if (g0 + 1 < p.M) sti(&p.rowscan[g0 + 1], excl + e0);
        if (tid == 255) sti(&p.bsums[bid], incl);
    } else if (bid >= nscan + 2 && bid < nscan + 2 + 2 * NLVL + NB) {
        int j = bid - (nscan + 2);
        const int* sA; int* dA;
        if (j < NLVL)          { sA = p.cntf + j * NBLK;              dA = p.blkf + j * NBLK; }
        else if (j < 2 * NLVL) { sA = p.cntb + (j - NLVL) * NBLK;     dA = p.blkb + (j - NLVL) * NBLK; }
        else                   { sA = p.cnto + (j - 2 * NLVL) * NBLK; dA = p.blko + (j - 2 * NLVL) * NBLK; }
        int v = sA[tid];
        int incl = blockScanIncl(v, s, tid);
        sti(&dA[tid], incl - v);
        if (tid == 255) sti(&p.meta[224 + j], incl);
    }
    gbar3(bar, FG, ++ep);

    // ---- P3: bsums -> bsums2 (write-once) + meta level bases -----------------
    if (bid == 0) {
        int i0 = tid * 4;
        int a0 = (i0     < nscan) ? p.bsums[i0]     : 0;
        int a1 = (i0 + 1 < nscan) ? p.bsums[i0 + 1] : 0;
        int a2 = (i0 + 2 < nscan) ? p.bsums[i0 + 2] : 0;
        int a3 = (i0 + 3 < nscan) ? p.bsums[i0 + 3] : 0;
        int incl = blockScanIncl(a0 + a1 + a2 + a3, s, tid);
        int b0 = incl - (a0 + a1 + a2 + a3);
        if (i0     < nscan) sti(&p.bsums2[i0],     b0);
        if (i0 + 1 < nscan) sti(&p.bsums2[i0 + 1], b0 + a0);
        if (i0 + 2 < nscan) sti(&p.bsums2[i0 + 2], b0 + a0 + a1);
        if (i0 + 3 < nscan) sti(&p.bsums2[i0 + 3], b0 + a0 + a1 + a2);
    } else if (bid == 1 && tid < 3) {
        if (tid == 0) { int a = 0; for (int l = 0; l < NLVL; l++) { sti(&p.meta[96 + l], a);  a += p.meta[224 + l]; }            sti(&p.meta[96 + NLVL], a); }
        if (tid == 1) { int a = 0; for (int l = 0; l < NLVL; l++) { sti(&p.meta[128 + l], a); a += p.meta[224 + NLVL + l]; }     sti(&p.meta[128 + NLVL], a); }
        if (tid == 2) { int a = 0; for (int l = 0; l < NB; l++)   { sti(&p.meta[160 + l], a); a += p.meta[224 + 2 * NLVL + l]; } sti(&p.meta[160 + NB], a); }
    }
    gbar3(bar, FG, ++ep);

    // ---- P4: FINAL rowptr/cursor (first-ever write of these arrays) + blkF ---
    for (int g = bid * 256 + tid; g < p.M; g += FG * 256) {
        int r = p.rowscan[g] + p.bsums2[g >> 9];
        sti(&p.rowptr[g], r);
        sti(&p.cursor[g], r);
    }
    if (bid == 0 && tid == 0) sti(&p.rowptr[p.M], 2 * p.E);
    for (int i = bid * 256 + tid; i < NLVL * NBLK; i += FG * 256) {
        sti(&p.blkFf[i], p.blkf[i] + p.meta[96 + (i >> 8)]);
        sti(&p.blkFb[i], p.blkb[i] + p.meta[128 + (i >> 8)]);
    }
    for (int i = bid * 256 + tid; i < NB * NBLK; i += FG * 256)
        sti(&p.blkFo[i], p.blko[i] + p.meta[160 + (i >> 8)]);
    gbar3(bar, FG, ++ep);

    // ---- P5: edge CSR fill (all blocks) + node bucket fill (round-6 proven) --
    for (int e = bid * 256 + tid; e < p.E; e += FG * 256) {
        int sN = p.src[e], d = p.dst[e];
        sti(&p.col[atomicAdd(&p.cursor[d], 1)],         sN | (p.plarr[sN] << 18));
        sti(&p.col[atomicAdd(&p.cursor[p.N + sN], 1)],   d | (p.plarr[d]  << 18));
    }
    if (bid < NBLK) {
        if (tid < NLVL) { cur[tid] = p.blkFf[tid * NBLK + bid]; cur[16 + tid] = p.blkFb[tid * NBLK + bid]; }
        if (tid < NB) cur[32 + tid] = p.blkFo[tid * NBLK + bid];
        __syncthreads();
        int chunk = (p.N + NBLK - 1) / NBLK;
        int lo = bid * chunk, hi = lo + chunk; if (hi > p.N) hi = p.N;
        for (int i = lo + tid; i < hi; i += 256) {
            int pl = p.plarr[i];
            int lf = pl & 15, lb = (pl >> 4) & 15, tx = (pl >> 8) & 15;
            int pk = i | (pl << 18);
            sti(&p.nb_f[atomicAdd(&cur[lf], 1)], pk);
            sti(&p.nb_b[atomicAdd(&cur[16 + lb], 1)], pk);
            if (tx >= 3 && tx < 6)
                sti(&p.onodes[atomicAdd(&cur[32 + p.batch[i]], 1)], pk);
        }
    }
    gbar3(bar, FG, ++ep);

    // ---- P6: 22 sweep levels, W loaded once per direction --------------------
    const int wid = (bid * 256 + tid) >> 6;
    const int nw  = (FG * 256) >> 6;
    const int q = lane >> 4, fb = (lane & 15) * 4;
    {
        float w[64];
        #pragma unroll
        for (int k = 0; k < 64; k++) w[k] = p.Wf[k * 64 + lane];
        float bv = p.bf[lane];
        for (int lvl = 1; lvl < NLVL; lvl++) {
            sweep_level<0>(p, lvl, w, bv, lane, wid, nw, q, fb);
            gbar3(bar, FG, ++ep);
        }
    }
    {
        float w[64];
        #pragma unroll
        for (int k = 0; k < 64; k++) w[k] = p.Wb[k * 64 + lane];
        float bv = p.bb[lane];
        for (int lvl = 1; lvl < NLVL; lvl++) {
            sweep_level<1>(p, lvl, w, bv, lane, wid, nw, q, fb);
            gbar3(bar, FG, ++ep);                       // incl. bar before readout
        }
    }

    // ---- P7: readout ---------------------------------------------------------
    if (bid < NB * 32) readout_body(p, bid, tid);
}

// ================= fallback multi-kernel path (round-0 proven) ================
__global__ void k_edge_deg(Params p) {
    int g = blockIdx.x * 256 + threadIdx.x, gs = gridDim.x * 256;
    for (int e = g; e < p.E; e += gs) {
        atomicAdd(&p.rowptr[p.dst[e]], 1);
        atomicAdd(&p.rowptr[p.N + p.src[e]], 1);
    }
}

__global__ void k_deg_hist(Params p) {
    __shared__ int hf[NLVL], hb[NLVL], ho[NB];
    int tid = threadIdx.x, bid = blockIdx.x;
    if (tid < NLVL) { hf[tid] = 0; hb[tid] = 0; }
    if (tid < NB) ho[tid] = 0;
    __syncthreads();
    int chunk = (p.N + gridDim.x - 1) / gridDim.x;
    int lo = bid * chunk, hi = lo + chunk; if (hi > p.N) hi = p.N;
    for (int i = lo + tid; i < hi; i += 256) {
        int f = p.fl[i], b = p.bl[i];
        int t = p.nt[i], iv = p.ninv[i];
        p.plarr[i] = f | (b << 4) | ((t * 3 + iv) << 8);
        atomicAdd(&hf[f], 1);
        atomicAdd(&hb[b], 1);
        if (t == 1) atomicAdd(&ho[p.batch[i]], 1);
    }
    __syncthreads();
    if (tid < NLVL) { p.cntf[tid * NBLK + bid] = hf[tid]; p.cntb[tid * NBLK + bid] = hb[tid]; }
    if (tid < NB) p.cnto[tid * NBLK + bid] = ho[tid];
}

__global__ void k_scan1(int* __restrict__ data, int M, int* __restrict__ bsums) {
    __shared__ int s[512];
    int t = threadIdx.x;
    int g = blockIdx.x * 512 + t;
    int v = (g < M) ? data[g] : 0;
    s[t] = v;
    __syncthreads();
    for (int off = 1; off < 512; off <<= 1) {
        int add = (t >= off) ? s[t - off] : 0;
        __syncthreads();
        s[t] += add;
        __syncthreads();
    }
    if (g < M) data[g] = s[t] - v;
    if (t == 511) bsums[blockIdx.x] = s[511];
}

__global__ void k_scan_top(int* __restrict__ bsums, int nblk, Params p,
                           float* __restrict__ out, int outN) {
    __shared__ int s[1024];
    __shared__ int tot[48];
    int t = threadIdx.x;
    int* meta = p.meta;
    for (int i = t; i < outN; i += 1024)
        out[i] = ((i & 127) < 64) ? -FLT_MAX : 0.0f;
    if (t < 576) {
        int row = t >> 6, j = t & 63;
        float nf = (float)(row / 3), iv = (float)(row % 3);
        p.tabg[t] = fmaf(nf, p.We[j], fmaf(iv, p.We[64 + j], p.be[j]));
    }
    int seg = t >> 8, b = t & 255;
    for (int r = 0; r < 3; r++) {
        int l = 4 * r + seg;
        int v = p.cntf[l * NBLK + b];
        s[t] = v; __syncthreads();
        for (int off = 1; off < NBLK; off <<= 1) {
            int add = (b >= off) ? s[t - off] : 0; __syncthreads();
            s[t] += add; __syncthreads();
        }
        p.blkf[l * NBLK + b] = s[t] - v;
        if (b == NBLK - 1) tot[l] = s[t];
        __syncthreads();
    }
    for (int r = 0; r < 3; r++) {
        int l = 4 * r + seg;
        int v = p.cntb[l * NBLK + b];
        s[t] = v; __syncthreads();
        for (int off = 1; off < NBLK; off <<= 1) {
            int add = (b >= off) ? s[t - off] : 0; __syncthreads();
            s[t] += add; __syncthreads();
        }
        p.blkb[l * NBLK + b] = s[t] - v;
        if (b == NBLK - 1) tot[16 + l] = s[t];
        __syncthreads();
    }
    for (int r = 0; r < 4; r++) {
        int l = 4 * r + seg;
        int v = p.cnto[l * NBLK + b];
        s[t] = v; __syncthreads();
        for (int off = 1; off < NBLK; off <<= 1) {
            int add = (b >= off) ? s[t - off] : 0; __syncthreads();
            s[t] += add; __syncthreads();
        }
        p.blko[l * NBLK + b] = s[t] - v;
        if (b == NBLK - 1) tot[32 + l] = s[t];
        __syncthreads();
    }
    if (t == 0) { int a = 0; for (int l = 0; l < NLVL; l++) { meta[96 + l] = a; a += tot[l]; } meta[96 + NLVL] = a; }
    if (t == 1) { int a = 0; for (int l = 0; l < NLVL; l++) { meta[128 + l] = a; a += tot[16 + l]; } meta[128 + NLVL] = a; }
    if (t == 2) { int a = 0; for (int l = 0; l < NB; l++) { meta[160 + l] = a; a += tot[32 + l]; } meta[160 + NB] = a; }
    __syncthreads();
    for (int i = t; i < NLVL * NBLK; i += 1024) p.blkf[i] += meta[96 + (i >> 8)];
    for (int i = t; i < NLVL * NBLK; i += 1024) p.blkb[i] += meta[128 + (i >> 8)];
    for (int i = t; i < NB * NBLK; i += 1024) p.blko[i] += meta[160 + (i >> 8)];
    int v = (t < nblk) ? bsums[t] : 0;
    s[t] = v;
    __syncthreads();
    for (int off = 1; off < 1024; off <<= 1) {
        int add = (t >= off) ? s[t - off] : 0;
        __syncthreads();
        s[t] += add;
        __syncthreads();
    }
    if (t < nblk) bsums[t] = s[t] - v;
}

__global__ void k_scan_add(int* __restrict__ rowptr, int* __restrict__ cursor, int M, int total,
                           const int* __restrict__ bsums) {
    int g = blockIdx.x * blockDim.x + threadIdx.x;
    if (g >= M) return;
    int r = rowptr[g] + bsums[g >> 9];
    rowptr[g] = r;
    cursor[g] = r;
    if (g == 0) rowptr[M] = total;
}

__global__ void k_edge_fill(Params p) {
    int g = blockIdx.x * 256 + threadIdx.x, gs = gridDim.x * 256;
    int N = p.N;
    for (int e = g; e < p.E; e += gs) {
        int s = p.src[e], d = p.dst[e];
        p.col[atomicAdd(&p.cursor[d], 1)] = s | (p.plarr[s] << 18);
        p.col[atomicAdd(&p.cursor[N + s], 1)] = d | (p.plarr[d] << 18);
    }
}

__global__ void k_fill(Params p) {
    __shared__ int cur[48];
    int tid = threadIdx.x, bid = blockIdx.x;
    int N = p.N;
    if (tid < NLVL) { cur[tid] = p.blkf[tid * NBLK + bid]; cur[16 + tid] = p.blkb[tid * NBLK + bid]; }
    if (tid < NB) cur[32 + tid] = p.blko[tid * NBLK + bid];
    __syncthreads();
    int chunk = (N + gridDim.x - 1) / gridDim.x;
    int lo = bid * chunk, hi = lo + chunk; if (hi > N) hi = N;
    for (int i = lo + tid; i < hi; i += 256) {
        int pl = p.plarr[i];
        int lf = pl & 15, lb = (pl >> 4) & 15, tx = (pl >> 8) & 15;
        int pk = i | (pl << 18);
        p.nb_f[atomicAdd(&cur[lf], 1)] = pk;
        p.nb_b[atomicAdd(&cur[16 + lb], 1)] = pk;
        if (tx >= 3 && tx < 6)
            p.onodes[atomicAdd(&cur[32 + p.batch[i]], 1)] = pk;
    }
}

__global__ __launch_bounds__(256) __attribute__((amdgpu_waves_per_eu(4, 4)))
void k_sweep(Params p, int lvl, int dir) {
    const int tid = threadIdx.x, lane = tid & 63;
    const float* W = dir ? p.Wb : p.Wf;
    float w[64];
    #pragma unroll
    for (int k = 0; k < 64; k++) w[k] = W[k * 64 + lane];
    float bv = (dir ? p.bb : p.bf)[lane];
    const int wid = (blockIdx.x * 256 + tid) >> 6;
    const int nw  = (gridDim.x * 256) >> 6;
    const int q = lane >> 4, fb = (lane & 15) * 4;
    if (dir == 0) sweep_level<0>(p, lvl, w, bv, lane, wid, nw, q, fb);
    else          sweep_level<1>(p, lvl, w, bv, lane, wid, nw, q, fb);
}

__global__ void k_readout(Params p) {
    readout_body(p, blockIdx.x, threadIdx.x);
}

extern "C" void kernel_launch(void* const* d_in, const int* in_sizes, int n_in,
                              void* d_out, int out_size, void* d_ws, size_t ws_size,
                              hipStream_t stream) {
    int N = in_sizes[0];
    int E = in_sizes[2] / 2;
    int M = 2 * N;

    Params p;
    p.nt    = (const int*)d_in[0];
    p.ninv  = (const int*)d_in[1];
    p.src   = (const int*)d_in[2];
    p.dst   = (const int*)d_in[2] + E;
    p.fl    = (const int*)d_in[3];
    p.bl    = (const int*)d_in[4];
    p.batch = (const int*)d_in[5];
    p.We    = (const float*)d_in[6];
    p.be    = (const float*)d_in[7];
    p.Wf    = (const float*)d_in[8];
    p.bf    = (const float*)d_in[9];
    p.Wb    = (const float*)d_in[10];
    p.bb    = (const float*)d_in[11];
    p.out   = (float*)d_out;
    p.N = N; p.E = E; p.M = M; p.outN = out_size;

    char* ws = (char*)d_ws;
    size_t off = 0;
    auto alloc = [&](size_t bytes) -> char* {
        char* q = ws + off;
        off = (off + bytes + 255) & ~(size_t)255;
        return q;
    };
    // rowptr + deg + meta + bar adjacent -> one memset zeroes all
    // (rowptr zero only needed by fallback; deg by fused P1; bar+meta by both)
    p.rowptr = (int*)  alloc((size_t)(M + 1) * sizeof(int));
    p.deg    = (int*)  alloc((size_t)M * sizeof(int));
    p.meta   = (int*)  alloc(512 * sizeof(int));
    p.bar    = (int*)  alloc((size_t)(18 + FG) * 32 * sizeof(int));
    size_t zbytes = (size_t)((char*)(p.bar + (18 + FG) * 32) - (char*)p.rowptr);
    p.hN     = (float*)alloc((size_t)N * 64 * sizeof(float));
    p.hB     = (float*)alloc((size_t)N * 64 * sizeof(float));
    p.tabg   = (float*)alloc(9 * 64 * sizeof(float));
    p.cursor = (int*)  alloc((size_t)M * sizeof(int));
    p.rowscan= (int*)  alloc((size_t)M * sizeof(int));
    p.col    = (int*)  alloc((size_t)2 * E * sizeof(int));
    p.nb_f   = (int*)  alloc((size_t)N * sizeof(int));
    p.nb_b   = (int*)  alloc((size_t)N * sizeof(int));
    p.onodes = (int*)  alloc((size_t)N * sizeof(int));
    p.plarr  = (int*)  alloc((size_t)N * sizeof(int));
    p.bsums  = (int*)  alloc(1024 * sizeof(int));
    p.bsums2 = (int*)  alloc(1024 * sizeof(int));
    p.cntf   = (int*)  alloc(NLVL * NBLK * sizeof(int));
    p.cntb   = (int*)  alloc(NLVL * NBLK * sizeof(int));
    p.cnto   = (int*)  alloc(NB * NBLK * sizeof(int));
    p.blkf   = (int*)  alloc(NLVL * NBLK * sizeof(int));
    p.blkb   = (int*)  alloc(NLVL * NBLK * sizeof(int));
    p.blko   = (int*)  alloc(NB * NBLK * sizeof(int));
    p.blkFf  = (int*)  alloc(NLVL * NBLK * sizeof(int));
    p.blkFb  = (int*)  alloc(NLVL * NBLK * sizeof(int));
    p.blkFo  = (int*)  alloc(NB * NBLK * sizeof(int));

    int nscan = (M + 511) / 512;            // 782 <= 1024

    // fused path requires co-residency of the full FG grid (round-4/6 proven probe)
    static int g_fused = -2;
    if (g_fused == -2) {
        int mb = 0;
        g_fused = 0;
        if (hipOccupancyMaxActiveBlocksPerMultiprocessor(&mb, k_fused, 256, 0) == hipSuccess
                && mb > 0) {
            int dev = 0;
            hipGetDevice(&dev);
            hipDeviceProp_t props;
            if (hipGetDeviceProperties(&props, dev) == hipSuccess &&
                (long)mb * props.multiProcessorCount >= FG)
                g_fused = 1;
        }
    }

    hipMemsetAsync(p.rowptr, 0, zbytes, stream);
    if (g_fused == 1) {
        k_fused<<<FG, 256, 0, stream>>>(p);
    } else {
        k_edge_deg<<<EBLK, 256, 0, stream>>>(p);
        k_deg_hist<<<NBLK, 256, 0, stream>>>(p);
        k_scan1<<<nscan, 512, 0, stream>>>(p.rowptr, M, p.bsums);
        k_scan_top<<<1, 1024, 0, stream>>>(p.bsums, nscan, p, p.out, out_size);
        k_scan_add<<<(M + 255) / 256, 256, 0, stream>>>(p.rowptr, p.cursor, M, 2 * E, p.bsums);
        k_edge_fill<<<EBLK, 256, 0, stream>>>(p);
        k_fill<<<NBLK, 256, 0, stream>>>(p);
        for (int l = 1; l < NLVL; l++)
            k_sweep<<<1024, 256, 0, stream>>>(p, l, 0);
        for (int l = 1; l < NLVL; l++)
            k_sweep<<<1024, 256, 0, stream>>>(p, l, 1);
        k_readout<<<NB * 32, 256, 0, stream>>>(p);
    }
}